// Round 9
// baseline (398.952 us; speedup 1.0000x reference)
//
#include <hip/hip_runtime.h>
#include <hip/hip_bf16.h>

// ---------------- types ----------------
typedef _Float16 half8 __attribute__((ext_vector_type(8)));
typedef _Float16 half4 __attribute__((ext_vector_type(4)));
typedef float floatx4 __attribute__((ext_vector_type(4)));

#define MFMA16(a, b, c) __builtin_amdgcn_mfma_f32_16x16x32_f16(a, b, c, 0, 0, 0)
#define GLDS16(gp, lp) __builtin_amdgcn_global_load_lds( \
    (const __attribute__((address_space(1))) void*)(gp), \
    (__attribute__((address_space(3))) void*)(lp), 16, 0, 0)

// Problem constants
#define BATCH 128
#define NTOK 197
#define NPAD 208                    // padded tokens per batch (mult of 16)
#define DIM 768
#define NH 12
#define DH 64
#define M_ROWS (BATCH * NTOK)       // 25216 (compact, for proj)
#define MP_ROWS (BATCH * NPAD)      // 26624 (padded, for qkv)
#define KPAD 224                    // padded key count for PV (7 * 32)
#define NKT 13                      // key tiles of 16 (13*16 = 208)

// prep kernel flat ranges (in half8 chunks / elements)
#define PREP_X (MP_ROWS * (DIM / 8))            // 2,555,904 x-pad chunks
#define PREP_WQ (3 * DIM * DIM / 8)             //   221,184 qkv_w chunks
#define PREP_WP (DIM * DIM / 8)                 //    73,728 proj_w chunks
#define PREP_B (NH * 13 * 13 * 256)             //   519,168 bias elements
#define PREP_VZ (BATCH * NH * DH * 2)           //   196,608 vt pad-col chunks
#define PREP_TOT (PREP_X + PREP_WQ + PREP_WP + PREP_B + PREP_VZ)

// raw barrier / counted waits (no compiler vmcnt(0) drain)
#define BAR() __asm__ volatile("s_barrier" ::: "memory")
#define VMW6() __asm__ volatile("s_waitcnt vmcnt(6)" ::: "memory")
#define VMW0() __asm__ volatile("s_waitcnt vmcnt(0)" ::: "memory")

// stage one 128x64 half-tile: 2 x global_load_lds(16B) per thread
#define STG(gp, lp) do { \
    GLDS16((gp), (lp)); \
    GLDS16((gp) + 64 * DIM, (lp) + 4096); } while (0)

// ---------------- fused prep: x pad-convert + weight converts + bias pack ----
__device__ __forceinline__ half8 cvt8(const float* s) {
    float4 v0 = *(const float4*)s;
    float4 v1 = *(const float4*)(s + 4);
    half8 o;
    o[0] = (_Float16)v0.x; o[1] = (_Float16)v0.y;
    o[2] = (_Float16)v0.z; o[3] = (_Float16)v0.w;
    o[4] = (_Float16)v1.x; o[5] = (_Float16)v1.y;
    o[6] = (_Float16)v1.z; o[7] = (_Float16)v1.w;
    return o;
}

__global__ void prep_kernel(const float* __restrict__ x,
                            const float* __restrict__ qkv_w,
                            const float* __restrict__ proj_w,
                            const float* __restrict__ table,
                            const int* __restrict__ ridx,
                            _Float16* __restrict__ xh,
                            _Float16* __restrict__ wqkvh,
                            _Float16* __restrict__ wprojh,
                            _Float16* __restrict__ biasph,
                            _Float16* __restrict__ vt) {
    int idx = blockIdx.x * 256 + threadIdx.x;
    if (idx < PREP_X) {
        // x: [128,197,768] f32 -> [128,208,768] f16 (pad rows = 0)
        int row = idx / (DIM / 8), ch = idx - row * (DIM / 8);
        int b = row / NPAD, n = row - b * NPAD;
        half8 o = {};
        if (n < NTOK) o = cvt8(x + (size_t)(b * NTOK + n) * DIM + ch * 8);
        *(half8*)&xh[(size_t)row * DIM + ch * 8] = o;
        return;
    }
    idx -= PREP_X;
    if (idx < PREP_WQ) {
        *(half8*)&wqkvh[idx * 8] = cvt8(qkv_w + idx * 8);
        return;
    }
    idx -= PREP_WQ;
    if (idx < PREP_WP) {
        *(half8*)&wprojh[idx * 8] = cvt8(proj_w + idx * 8);
        return;
    }
    idx -= PREP_WP;
    if (idx < PREP_B) {
        // biasph[(h*13+qt)*13+nt][r(16)][q(4)][rr(4)]; pad cols = -30000
        int e = idx & 255;
        int r = e >> 4, q = (e >> 2) & 3, rr = e & 3;
        int t = idx >> 8;
        int nt = t % 13; int t2 = t / 13; int qt = t2 % 13; int h = t2 / 13;
        int row = qt * 16 + q * 4 + rr;
        int col = nt * 16 + r;
        float v = -30000.0f;
        if (col < NTOK) {
            int rc = row < NTOK ? row : NTOK - 1;   // clamped rows: value unused
            v = table[ridx[rc * NTOK + col] * NH + h];
        }
        biasph[idx] = (_Float16)v;
        return;
    }
    idx -= PREP_B;
    if (idx < PREP_VZ) {
        // zero vt pad cols 208..223 so attn LDS staging reads defined data
        int row = idx >> 1, c = idx & 1;            // row = bh*64 + d
        half8 z = {};
        *(half8*)&vt[(size_t)row * KPAD + 208 + c * 8] = z;
    }
}

// =====================================================================
// QKV GEMM — 256x256 tile, BK=64, 8 waves (2M x 4N), 8-phase counted-vmcnt.
// SYMMETRIC 2-DEEP prefetch (both A and B staged t+2 ahead):
//   ph0: read A-lo + B-lo;  stage A(t+1).h1 -> other buf (its readers ended t-1.ph2)
//   ph1: read B-hi
//   ph2: read A-hi;         stage B(t+2).h0 -> SAME buf (B(t) reads ended ph1)
//   ph3:                    stage B(t+2).h1 + A(t+2).h0 -> SAME buf (A-lo reads ended ph0)
//   A(t+2).h1 rides in tile t+1's ph0.
// Tile-end wait: vmcnt(6) — the 6 newest loads are the t+2 ones; everything
// needed for t+1 (A(t+1).h1 and older) is forced complete. Every staged load
// gets >= 4 phases (~1 tile) of latency cover vs ~2 phases before.
// =====================================================================
template <int VM, bool SA1, bool SB2, bool SA2>
__device__ __forceinline__ void qkv_tile(int t, _Float16* smem,
                                         const _Float16* ga0, const _Float16* ga1,
                                         const _Float16* gb0, const _Float16* gb1,
                                         int sbase, int r, int q, int wm, int wn,
                                         floatx4 (&acc)[8][4]) {
    const int buf = t & 1;
    const int r7 = r & 7;
    const int sl0 = (q ^ r7) * 8;        // k-slice 0 swizzled 16B slot (elems)
    const int sl1 = sl0 ^ 32;            // k-slice 1 (slot ^ 4)
    _Float16* base = smem + buf * 32768;
    const _Float16* Ab = base + wm * 8192 + r * 64;
    const _Float16* Bb = base + 16384 + (wn >> 1) * 8192 + ((wn & 1) * 64 + r) * 64;
    _Float16* sA1h1 = smem + (buf ^ 1) * 32768 + 8192 + sbase;  // A(t+1) hi, other buf
    _Float16* sB0 = base + 16384 + sbase;                       // B(t+2) h0, same buf
    _Float16* sB1 = sB0 + 8192;                                 // B(t+2) h1
    _Float16* sA2h0 = base + sbase;                             // A(t+2) h0, same buf
    const int kof1 = (t + 1) * 64, kof2 = (t + 2) * 64;

    half8 a[4][2], b[4][2];

    // ---- phase 0: A rows 0..63 (i=0..3) + B cols 0..31 (j=0..1) ----
#pragma unroll
    for (int i = 0; i < 4; ++i) {
        a[i][0] = *(const half8*)(Ab + i * 1024 + sl0);
        a[i][1] = *(const half8*)(Ab + i * 1024 + sl1);
    }
#pragma unroll
    for (int j = 0; j < 2; ++j) {
        b[j][0] = *(const half8*)(Bb + j * 1024 + sl0);
        b[j][1] = *(const half8*)(Bb + j * 1024 + sl1);
    }
    if (SA1) STG(ga1 + kof1, sA1h1);
    BAR();
    __builtin_amdgcn_s_setprio(1);
#pragma unroll
    for (int s = 0; s < 2; ++s)
#pragma unroll
        for (int i = 0; i < 4; ++i)
#pragma unroll
            for (int j = 0; j < 2; ++j)
                acc[i][j] = MFMA16(a[i][s], b[j][s], acc[i][j]);
    __builtin_amdgcn_s_setprio(0);
    BAR();

    // ---- phase 1: B cols 32..63 (j=2..3) ----
#pragma unroll
    for (int j = 0; j < 2; ++j) {
        b[2 + j][0] = *(const half8*)(Bb + (2 + j) * 1024 + sl0);
        b[2 + j][1] = *(const half8*)(Bb + (2 + j) * 1024 + sl1);
    }
    BAR();
    __builtin_amdgcn_s_setprio(1);
#pragma unroll
    for (int s = 0; s < 2; ++s)
#pragma unroll
        for (int i = 0; i < 4; ++i)
#pragma unroll
            for (int j = 0; j < 2; ++j)
                acc[i][2 + j] = MFMA16(a[i][s], b[2 + j][s], acc[i][2 + j]);
    __builtin_amdgcn_s_setprio(0);
    BAR();

    // ---- phase 2: A rows 64..127 (i=4..7) ----
#pragma unroll
    for (int i = 0; i < 4; ++i) {
        a[i][0] = *(const half8*)(Ab + (4 + i) * 1024 + sl0);
        a[i][1] = *(const half8*)(Ab + (4 + i) * 1024 + sl1);
    }
    if (SB2) STG(gb0 + kof2, sB0);
    BAR();
    __builtin_amdgcn_s_setprio(1);
#pragma unroll
    for (int s = 0; s < 2; ++s)
#pragma unroll
        for (int i = 0; i < 4; ++i)
#pragma unroll
            for (int j = 0; j < 2; ++j)
                acc[4 + i][j] = MFMA16(a[i][s], b[j][s], acc[4 + i][j]);
    __builtin_amdgcn_s_setprio(0);
    BAR();

    // ---- phase 3 ----
    if (SB2) STG(gb1 + kof2, sB1);
    if (SA2) STG(ga0 + kof2, sA2h0);
    BAR();
    __builtin_amdgcn_s_setprio(1);
#pragma unroll
    for (int s = 0; s < 2; ++s)
#pragma unroll
        for (int i = 0; i < 4; ++i)
#pragma unroll
            for (int j = 0; j < 2; ++j)
                acc[4 + i][2 + j] = MFMA16(a[i][s], b[2 + j][s], acc[4 + i][2 + j]);
    __builtin_amdgcn_s_setprio(0);
    if (VM == 6) { VMW6(); }
    else if (VM == 0) { VMW0(); }
    BAR();
}

__global__ __launch_bounds__(512, 2) void qkv_gemm8(const _Float16* __restrict__ X,
                                                    const _Float16* __restrict__ W,
                                                    _Float16* __restrict__ qh,
                                                    _Float16* __restrict__ kh,
                                                    _Float16* __restrict__ vt) {
    __shared__ __align__(16) _Float16 smem[65536];   // 128 KiB
    const int tid = threadIdx.x;
    const int lane = tid & 63, wid = tid >> 6;
    const int r = lane & 15, q = lane >> 4;
    const int wm = wid >> 2, wn = wid & 3;

    // bijective XCD swizzle: 936 blocks = 8 XCDs x (13 M-bands x 9 col-blocks)
    const int id = blockIdx.x;
    const int swz = (id & 7) * 117 + (id >> 3);
    const int by = swz / 9, bx = swz - by * 9;
    const int m0b = by * 256, n0b = bx * 256;

    // staging addresses: row = wid*8 + lane/8 (+64 for round 1), pre-swizzled chunk
    const int srow = wid * 8 + (lane >> 3);
    const int sch = (lane & 7) ^ (lane >> 3);
    const _Float16* ga0 = X + (size_t)(m0b + srow) * DIM + sch * 8;
    const _Float16* ga1 = ga0 + (size_t)128 * DIM;
    const _Float16* gb0 = W + (size_t)(n0b + srow) * DIM + sch * 8;
    const _Float16* gb1 = gb0 + (size_t)128 * DIM;
    const int sbase = wid * 512;         // wave-uniform LDS base (elems)

    floatx4 acc[8][4] = {};

    // prologue: A0 full + B0 full + B1 full + A1.h0; wait all but the 6 newest
    STG(ga0, smem + sbase);                          // A0 h0
    STG(ga1, smem + 8192 + sbase);                   // A0 h1
    STG(gb0, smem + 16384 + sbase);                  // B0 h0
    STG(gb1, smem + 24576 + sbase);                  // B0 h1
    STG(gb0 + 64, smem + 32768 + 16384 + sbase);     // B1 h0
    STG(gb1 + 64, smem + 32768 + 24576 + sbase);     // B1 h1
    STG(ga0 + 64, smem + 32768 + sbase);             // A1 h0
    VMW6();                                          // A0,B0 done; B1,A1.h0 in flight
    BAR();

#pragma unroll 2
    for (int t = 0; t < 10; ++t)
        qkv_tile<6, true, true, true>(t, smem, ga0, ga1, gb0, gb1, sbase, r, q, wm, wn, acc);
    qkv_tile<0, true, false, false>(10, smem, ga0, ga1, gb0, gb1, sbase, r, q, wm, wn, acc);
    qkv_tile<-1, false, false, false>(11, smem, ga0, ga1, gb0, gb1, sbase, r, q, wm, wn, acc);

    // ---- epilogue: transpose via LDS, two row-half passes ----
    __syncthreads();
    const int which = bx / 3;                 // 0=q 1=k 2=v
    const int cb = (bx - which * 3) * 256;    // col base within 768-block
    if (which == 2) {
#pragma unroll
        for (int hp = 0; hp < 2; ++hp) {
            if (wm == hp) {
                // T[c][g] pitch 136: c = col, g = row-in-half
#pragma unroll
                for (int i = 0; i < 8; ++i)
#pragma unroll
                    for (int j = 0; j < 4; ++j) {
                        half4 hv;
#pragma unroll
                        for (int rr = 0; rr < 4; ++rr) hv[rr] = (_Float16)acc[i][j][rr];
                        *(half4*)&smem[(wn * 64 + j * 16 + r) * 136 + i * 16 + q * 4] = hv;
                    }
            }
            __syncthreads();
#pragma unroll
            for (int p = 0; p < 8; ++p) {
                int idx = p * 512 + tid;
                int c = idx >> 4, g0 = (idx & 15) * 8;
                int grow = m0b + hp * 128 + g0;
                int b_idx = grow / NPAD, n_idx = grow - b_idx * NPAD;
                int vcol = cb + c;
                int hh = vcol >> 6, d = vcol & 63;
                half8 hv = *(const half8*)&smem[c * 136 + g0];
                *(half8*)&vt[((size_t)(b_idx * NH + hh) * DH + d) * KPAD + n_idx] = hv;
            }
            __syncthreads();
        }
    } else {
        const float scale = (which == 0) ? 0.125f : 1.0f;  // 64^-0.5 folded into q
        _Float16* dst = (which == 0) ? qh : kh;
#pragma unroll
        for (int hp = 0; hp < 2; ++hp) {
            if (wm == hp) {
                // T[g][c] pitch 272 (row stride 16 dwords mod 32 banks: conflict-free)
#pragma unroll
                for (int i = 0; i < 8; ++i)
#pragma unroll
                    for (int j = 0; j < 4; ++j)
#pragma unroll
                        for (int rr = 0; rr < 4; ++rr)
                            smem[(i * 16 + q * 4 + rr) * 272 + wn * 64 + j * 16 + r] =
                                (_Float16)(acc[i][j][rr] * scale);
            }
            __syncthreads();
#pragma unroll
            for (int p = 0; p < 8; ++p) {
                int idx = p * 512 + tid;
                int g = idx >> 5, c0 = (idx & 31) * 8;
                int grow = m0b + hp * 128 + g;
                int b_idx = grow / NPAD, n_idx = grow - b_idx * NPAD;
                int colm = cb + c0;
                int hh = colm >> 6, d0 = colm & 63;
                half8 hv = *(const half8*)&smem[g * 272 + c0];
                *(half8*)&dst[((size_t)(b_idx * NH + hh) * NPAD + n_idx) * DH + d0] = hv;
            }
            __syncthreads();
        }
    }
}

// =====================================================================
// m97-style GEMM core (kept for proj): 128x128 tile, BK=64, swizzled atoms.
// =====================================================================
__device__ __forceinline__ void gemm_core_768(const _Float16* __restrict__ A,
                                              const _Float16* __restrict__ B,
                                              int m0b, int n0b,
                                              _Float16* As, _Float16* Bs,
                                              floatx4 acc[4][4]) {
    const int lane = threadIdx.x & 63;
    const int w = threadIdx.x >> 6;
    const int r = lane & 15, q = lane >> 4;
    const int mo = (w & 1) * 64;                    // wave sub-tile row offset in A
    const int no = (w >> 1) * 64;                   // wave sub-tile row offset in B
    const int srow = w * 32 + (lane >> 3);          // staging row (per chunk +8)
    const int gatom = (lane & 7) ^ (lane >> 3);     // swizzled k-atom this lane fetches
    const int rx = r & 7;

    const _Float16* pa[4];
    const _Float16* pb[4];
#pragma unroll
    for (int c = 0; c < 4; ++c) {
        pa[c] = A + (size_t)(m0b + srow + c * 8) * DIM + gatom * 8;
        pb[c] = B + (size_t)(n0b + srow + c * 8) * DIM + gatom * 8;
    }
    _Float16* ldsA = As + w * 2048;
    _Float16* ldsB = Bs + w * 2048;

    for (int kk = 0; kk < DIM / 64; ++kk) {
#pragma unroll
        for (int c = 0; c < 4; ++c) {
            GLDS16(pa[c], ldsA + c * 512);
            GLDS16(pb[c], ldsB + c * 512);
            pa[c] += 64;
            pb[c] += 64;
        }
        __syncthreads();
#pragma unroll
        for (int s = 0; s < 2; ++s) {
            half8 a[4], b[4];
#pragma unroll
            for (int i = 0; i < 4; ++i)
                a[i] = *(const half8*)&As[((mo + i * 16 + r) * 8 + ((s * 4 + q) ^ rx)) * 8];
#pragma unroll
            for (int j = 0; j < 4; ++j)
                b[j] = *(const half8*)&Bs[((no + j * 16 + r) * 8 + ((s * 4 + q) ^ rx)) * 8];
#pragma unroll
            for (int i = 0; i < 4; ++i)
#pragma unroll
                for (int j = 0; j < 4; ++j)
                    acc[i][j] = MFMA16(a[i], b[j], acc[i][j]);
        }
        __syncthreads();
    }
}

// ---------------- proj GEMM: [25216,768] x [768,768]^T + bias -> fp32 out ----------------
__global__ __launch_bounds__(256) void proj_gemm(const _Float16* __restrict__ A,
                                                 const _Float16* __restrict__ W,
                                                 const float* __restrict__ bias,
                                                 float* __restrict__ out) {
    __shared__ __align__(16) _Float16 As[128 * 64];
    __shared__ __align__(16) _Float16 Bs[128 * 64];
    const int lane = threadIdx.x & 63;
    const int w = threadIdx.x >> 6;
    const int r = lane & 15, q = lane >> 4;

    const int id = blockIdx.x;
    const int xcd = id & 7;
    const int lid = id >> 3;
    const int bx = lid % 6;
    const int by = xcd * 25 + lid / 6;
    if (by >= 197) return;                   // whole block exits: no barrier hazard
    const int m0b = by * 128;
    const int n0b = bx * 128;

    floatx4 acc[4][4] = {};
    gemm_core_768(A, W, m0b, n0b, As, Bs, acc);

    const int m0 = m0b + (w & 1) * 64;
    const int n0 = n0b + (w >> 1) * 64;
#pragma unroll
    for (int i = 0; i < 4; ++i) {
#pragma unroll
        for (int rr = 0; rr < 4; ++rr) {
            size_t grow = m0 + i * 16 + q * 4 + rr;
#pragma unroll
            for (int j = 0; j < 4; ++j) {
                int gcol = n0 + j * 16 + r;
                out[grow * DIM + gcol] = acc[i][j][rr] + bias[gcol];
            }
        }
    }
}

// ---------------- attention: block = one (b,h); K/V staged in LDS ----------
// 13 waves (832 thr), wave w owns q-tile w. K [208][8ch] and V^T [64][32ch]
// staged via global_load_lds with row-low-3-bit XOR chunk swizzle
// (pre-swizzled GLOBAL source, linear LDS dest; reads apply the same XOR).
// All GLDS issues are FULL-WAVE; out-of-range source chunks clamped to 0
// (slots provably never read). Bias = MFMA C-init; exp immediately per nt;
// P stored UNNORMALIZED in half; 1/rowsum folded into final O scale.
__global__ __launch_bounds__(832, 7) void attn_kernel(const _Float16* __restrict__ qh,
                                                      const _Float16* __restrict__ kh,
                                                      const _Float16* __restrict__ vt,
                                                      const _Float16* __restrict__ biasph,
                                                      _Float16* __restrict__ ah) {
    __shared__ __align__(16) _Float16 smem[38016];   // 76 KB: K 26.6K | V 32.8K | P 16.6K
    _Float16* Ks = smem;                  // [208][8 chunks swz]
    _Float16* Vs = smem + 13312;          // [64][32 chunks swz, 28 valid]
    _Float16* Pb = smem + 29696;          // [13][16][40]
    const int tid = threadIdx.x;
    const int w = tid >> 6, lane = tid & 63;
    const int r = lane & 15, q = lane >> 4;
    const int xr = r & 7;
    const int bh = ((blockIdx.x & 7) * 192) + (blockIdx.x >> 3);  // XCD-contiguous
    const int b = bh / NH, h = bh - b * NH;
    const _Float16* Kb = kh + (size_t)bh * NPAD * DH;
    const _Float16* Vtb = vt + (size_t)bh * DH * KPAD;

    // ---- stage K: 1664 slots, 2 exact full-wave rounds; src chunk = pos ^ (row&7)
#pragma unroll
    for (int rd = 0; rd < 2; ++rd) {
        int i = rd * 832 + tid;
        int g = i >> 3;
        int cs = (i & 7) ^ (g & 7);
        GLDS16(Kb + (size_t)g * DH + cs * 8, Ks + (rd * 832 + w * 64) * 8);
    }
    // ---- stage V: 2048 slots (pitch 32); rd=2 guard tid<384 = wave boundary
#pragma unroll
    for (int rd = 0; rd < 3; ++rd) {
        int j = rd * 832 + tid;
        if (j < 2048) {
            int g = j >> 5;
            int cs = (j & 31) ^ (g & 7);
            if (cs >= 28) cs = 0;       // branch-free select; slot never read
            GLDS16(Vtb + (size_t)g * KPAD + cs * 8, Vs + (rd * 832 + w * 64) * 8);
        }
    }
    __syncthreads();   // vmcnt(0) drain + barrier: staged data visible

    // ---- per-wave q-tile (qt = w) ----
    const int rowq = w * 16 + r;
    const _Float16* Qb = qh + (size_t)bh * NPAD * DH;
    half8 aq0 = *(const half8*)(Qb + (size_t)rowq * DH + q * 8);
    half8 aq1 = *(const half8*)(Qb + (size_t)rowq * DH + 32 + q * 8);

    // S = QK^T + bias (C-init), exp immediately -> unnormalized P (half)
    const _Float16* bbase = biasph + (((size_t)h * 13 + w) * 13) * 256 + r * 16 + q * 4;
    half4 pvh[NKT + 1];
    float osum[4] = {0.f, 0.f, 0.f, 0.f};
#pragma unroll
    for (int nt = 0; nt < NKT; ++nt) {
        half4 bv = *(const half4*)(bbase + nt * 256);
        floatx4 acc;
        acc[0] = (float)bv[0]; acc[1] = (float)bv[1];
        acc[2] = (float)bv[2]; acc[3] = (float)bv[3];
        const _Float16* kr = Ks + (nt * 16 + r) * 64;
        half8 b0 = *(const half8*)(kr + (q ^ xr) * 8);
        half8 b1 = *(const half8*)(kr + ((q ^ xr) ^ 4) * 8);
        acc = MFMA16(aq0, b0, acc);
        acc = MFMA16(aq1, b1, acc);
        half4 e4;
#pragma unroll
        for (int rr = 0; rr < 4; ++rr) {
            float e = __expf(acc[rr]);      // pad cols: exp(-30000) == 0 exactly
            osum[rr] += e;
            e4[rr] = (_Float16)e;
        }
        pvh[nt] = e4;
    }
    {
        half4 z = {};
        pvh[NKT] = z;                       // tail slot for kt=6
    }
    // row-sum across the 16 key-lanes (r bits 0..3)
#pragma unroll
    for (int rr = 0; rr < 4; ++rr) {
#pragma unroll
        for (int m = 1; m <= 8; m <<= 1) osum[rr] += __shfl_xor(osum[rr], m, 64);
    }

    // O = P V (P unnormalized), chunked over 7 x 32 keys; P via wave-private LDS
    floatx4 oacc[4] = {};
    _Float16* Pw = Pb + w * 640;
#pragma unroll
    for (int kt = 0; kt < 7; ++kt) {
#pragma unroll
        for (int rr = 0; rr < 4; ++rr) {
            Pw[(q * 4 + rr) * 40 + r] = pvh[kt * 2][rr];
            Pw[(q * 4 + rr) * 40 + 16 + r] = pvh[kt * 2 + 1][rr];
        }
        __asm__ volatile("" ::: "memory");   // keep ds_write -> ds_read order
        half8 ap = *(const half8*)&Pw[r * 40 + q * 8];
        __asm__ volatile("" ::: "memory");   // keep ds_read -> next writes order
#pragma unroll
        for (int dt = 0; dt < 4; ++dt) {
            half8 bv = *(const half8*)(Vs + (dt * 16 + r) * 256 + (((kt * 4 + q) ^ xr) * 8));
            oacc[dt] = MFMA16(ap, bv, oacc[dt]);
        }
    }

    // store (pad rows masked), fold 1/rowsum here
#pragma unroll
    for (int rr = 0; rr < 4; ++rr) {
        int row = w * 16 + q * 4 + rr;
        if (row < NTOK) {
            float inv = 1.0f / osum[rr];
            size_t o = ((size_t)b * NTOK + row) * DIM + h * DH;
#pragma unroll
            for (int dt = 0; dt < 4; ++dt)
                ah[o + dt * 16 + r] = (_Float16)(oacc[dt][rr] * inv);
        }
    }
}

// ---------------- launch ----------------
extern "C" void kernel_launch(void* const* d_in, const int* in_sizes, int n_in,
                              void* d_out, int out_size, void* d_ws, size_t ws_size,
                              hipStream_t stream) {
    const float* x = (const float*)d_in[0];        // [128,197,768]
    const float* qkv_w = (const float*)d_in[1];    // [2304,768]
    const float* proj_w = (const float*)d_in[2];   // [768,768]
    const float* proj_b = (const float*)d_in[3];   // [768]
    const float* table = (const float*)d_in[4];    // [730,12]
    const int* ridx = (const int*)d_in[5];         // [197,197]
    float* out = (float*)d_out;

    char* ws = (char*)d_ws;
    const size_t SZ_XP = (size_t)MP_ROWS * DIM * 2;             // 40.9 MB (padded f16)
    const size_t SZ_WQKV = (size_t)3 * DIM * DIM * 2;           //  3.5 MB
    const size_t SZ_WPROJ = (size_t)DIM * DIM * 2;              //  1.2 MB
    const size_t SZ_QK = (size_t)BATCH * NH * NPAD * DH * 2;    // 40.9 MB each
    const size_t SZ_VT = (size_t)BATCH * NH * DH * KPAD * 2;    // 44.0 MB
    const size_t SZ_BIAS = (size_t)NH * 13 * 13 * 256 * 2;      //  1.0 MB

    _Float16* xh = (_Float16*)(ws + 0);
    _Float16* ah = (_Float16*)(ws + 0);              // aliases xh (x dead after qkv)
    _Float16* wqkvh = (_Float16*)(ws + SZ_XP);
    _Float16* wprojh = (_Float16*)(ws + SZ_XP + SZ_WQKV);
    _Float16* qh = (_Float16*)(ws + SZ_XP + SZ_WQKV + SZ_WPROJ);
    _Float16* kh = (_Float16*)(ws + SZ_XP + SZ_WQKV + SZ_WPROJ + SZ_QK);
    _Float16* vt = (_Float16*)(ws + SZ_XP + SZ_WQKV + SZ_WPROJ + 2 * SZ_QK);
    _Float16* biasph = (_Float16*)(ws + SZ_XP + SZ_WQKV + SZ_WPROJ + 2 * SZ_QK + SZ_VT);
    (void)SZ_BIAS; (void)ws_size; (void)n_in; (void)in_sizes; (void)out_size;

    // fused prep: x pad-convert + weight converts + bias pack + vt pad-col zero
    prep_kernel<<<(PREP_TOT + 255) / 256, 256, 0, stream>>>(
        x, qkv_w, proj_w, table, ridx, xh, wqkvh, wprojh, biasph, vt);
    // qkv gemm: 256^2 8-phase, symmetric 2-deep prefetch, vmcnt(6)
    qkv_gemm8<<<936, 512, 0, stream>>>(xh, wqkvh, qh, kh, vt);
    // attention: one block per (b,h), 13 waves, K/V LDS-staged
    attn_kernel<<<BATCH * NH, 832, 0, stream>>>(qh, kh, vt, biasph, ah);
    // proj gemm (XCD-swizzled, guarded)
    proj_gemm<<<1200, 256, 0, stream>>>(ah, wprojh, proj_b, out);
}

// Round 11
// 396.617 us; speedup vs baseline: 1.0059x; 1.0059x over previous
//
#include <hip/hip_runtime.h>
#include <hip/hip_bf16.h>

// ---------------- types ----------------
typedef _Float16 half8 __attribute__((ext_vector_type(8)));
typedef _Float16 half4 __attribute__((ext_vector_type(4)));
typedef float floatx4 __attribute__((ext_vector_type(4)));

#define MFMA16(a, b, c) __builtin_amdgcn_mfma_f32_16x16x32_f16(a, b, c, 0, 0, 0)
#define GLDS16(gp, lp) __builtin_amdgcn_global_load_lds( \
    (const __attribute__((address_space(1))) void*)(gp), \
    (__attribute__((address_space(3))) void*)(lp), 16, 0, 0)

// Problem constants
#define BATCH 128
#define NTOK 197
#define NPAD 208                    // padded tokens per batch (mult of 16)
#define DIM 768
#define NH 12
#define DH 64
#define M_ROWS (BATCH * NTOK)       // 25216 (compact, for proj)
#define MP_ROWS (BATCH * NPAD)      // 26624 (padded, for qkv)
#define KPAD 224                    // padded key count for PV (7 * 32)
#define NKT 13                      // key tiles of 16 (13*16 = 208)

// prep kernel flat ranges (in half8 chunks / elements)
#define PREP_X (MP_ROWS * (DIM / 8))            // 2,555,904 x-pad chunks
#define PREP_WQ (3 * DIM * DIM / 8)             //   221,184 qkv_w chunks
#define PREP_WP (DIM * DIM / 8)                 //    73,728 proj_w chunks
#define PREP_B (NH * 13 * 13 * 256)             //   519,168 bias elements
#define PREP_VZ (BATCH * NH * DH * 2)           //   196,608 vt pad-col chunks
#define PREP_TOT (PREP_X + PREP_WQ + PREP_WP + PREP_B + PREP_VZ)

// raw barrier / counted waits (no compiler vmcnt(0) drain)
#define BAR() __asm__ volatile("s_barrier" ::: "memory")
#define VMW4() __asm__ volatile("s_waitcnt vmcnt(4)" ::: "memory")
#define VMW0() __asm__ volatile("s_waitcnt vmcnt(0)" ::: "memory")

// stage one 128x64 half-tile: 2 x global_load_lds(16B) per thread
#define STG(gp, lp) do { \
    GLDS16((gp), (lp)); \
    GLDS16((gp) + 64 * DIM, (lp) + 4096); } while (0)

// ---------------- fused prep: x pad-convert + weight converts + bias pack ----
__device__ __forceinline__ half8 cvt8(const float* s) {
    float4 v0 = *(const float4*)s;
    float4 v1 = *(const float4*)(s + 4);
    half8 o;
    o[0] = (_Float16)v0.x; o[1] = (_Float16)v0.y;
    o[2] = (_Float16)v0.z; o[3] = (_Float16)v0.w;
    o[4] = (_Float16)v1.x; o[5] = (_Float16)v1.y;
    o[6] = (_Float16)v1.z; o[7] = (_Float16)v1.w;
    return o;
}

__global__ void prep_kernel(const float* __restrict__ x,
                            const float* __restrict__ qkv_w,
                            const float* __restrict__ proj_w,
                            const float* __restrict__ table,
                            const int* __restrict__ ridx,
                            _Float16* __restrict__ xh,
                            _Float16* __restrict__ wqkvh,
                            _Float16* __restrict__ wprojh,
                            _Float16* __restrict__ biasph,
                            _Float16* __restrict__ vt) {
    int idx = blockIdx.x * 256 + threadIdx.x;
    if (idx < PREP_X) {
        // x: [128,197,768] f32 -> [128,208,768] f16 (pad rows = 0)
        int row = idx / (DIM / 8), ch = idx - row * (DIM / 8);
        int b = row / NPAD, n = row - b * NPAD;
        half8 o = {};
        if (n < NTOK) o = cvt8(x + (size_t)(b * NTOK + n) * DIM + ch * 8);
        *(half8*)&xh[(size_t)row * DIM + ch * 8] = o;
        return;
    }
    idx -= PREP_X;
    if (idx < PREP_WQ) {
        *(half8*)&wqkvh[idx * 8] = cvt8(qkv_w + idx * 8);
        return;
    }
    idx -= PREP_WQ;
    if (idx < PREP_WP) {
        *(half8*)&wprojh[idx * 8] = cvt8(proj_w + idx * 8);
        return;
    }
    idx -= PREP_WP;
    if (idx < PREP_B) {
        // biasph[(h*13+qt)*13+nt][r(16)][q(4)][rr(4)]; pad cols = -30000
        int e = idx & 255;
        int r = e >> 4, q = (e >> 2) & 3, rr = e & 3;
        int t = idx >> 8;
        int nt = t % 13; int t2 = t / 13; int qt = t2 % 13; int h = t2 / 13;
        int row = qt * 16 + q * 4 + rr;
        int col = nt * 16 + r;
        float v = -30000.0f;
        if (col < NTOK) {
            int rc = row < NTOK ? row : NTOK - 1;   // clamped rows: value unused
            v = table[ridx[rc * NTOK + col] * NH + h];
        }
        biasph[idx] = (_Float16)v;
        return;
    }
    idx -= PREP_B;
    if (idx < PREP_VZ) {
        // zero vt pad cols 208..223 so attn LDS staging reads defined data
        int row = idx >> 1, c = idx & 1;            // row = bh*64 + d
        half8 z = {};
        *(half8*)&vt[(size_t)row * KPAD + 208 + c * 8] = z;
    }
}

// =====================================================================
// QKV GEMM — 256x256 tile, BK=64, 8 waves (2M x 4N), TWO barriers/tile.
// Data schedule = round-7 proven one (A staged t+1 -> other buf, B staged
// t+2 -> current buf, vmcnt(4) at tile end). Barrier reduction 8 -> 2:
// every read in tile t targets regions whose writes completed before the
// tile began, so the only intra-tile ordering needed is
//   {all B reads} -> BAR -> {B(t+2) STG}.
// Structure per tile:
//   half 1: read A-lo(8) + B-all(8); STG A(t+1).h0+.h1 -> other buf;
//           32 MFMA (a-lo x b0..3)
//   BAR     (each wave's B reads are consumed by its MFMAs' lgkmcnt
//            before it arrives -> B region quiescent)
//   half 2: read A-hi(8); STG B(t+2).h0+.h1 -> current buf B region;
//           32 MFMA (a-hi x b0..3)
//   vmcnt(4) (leave only B(t+2)'s 4 loads in flight); BAR
// This lets waves slip within each half: one wave's ds_reads overlap other
// waves' MFMAs instead of the old all-read-then-all-MFMA lockstep.
// =====================================================================
template <int VM, bool SA, bool SB>
__device__ __forceinline__ void qkv_tile(int t, _Float16* smem,
                                         const _Float16* ga0, const _Float16* ga1,
                                         const _Float16* gb0, const _Float16* gb1,
                                         int sbase, int r, int q, int wm, int wn,
                                         floatx4 (&acc)[8][4]) {
    const int buf = t & 1;
    const int r7 = r & 7;
    const int sl0 = (q ^ r7) * 8;        // k-slice 0 swizzled 16B slot (elems)
    const int sl1 = sl0 ^ 32;            // k-slice 1 (slot ^ 4)
    _Float16* base = smem + buf * 32768;
    const _Float16* Ab = base + wm * 8192 + r * 64;
    const _Float16* Bb = base + 16384 + (wn >> 1) * 8192 + ((wn & 1) * 64 + r) * 64;
    _Float16* sA0 = smem + (buf ^ 1) * 32768 + sbase;       // A(t+1) h0, other buf
    _Float16* sA1 = sA0 + 8192;                             // A(t+1) h1
    _Float16* sB0 = base + 16384 + sbase;                   // B(t+2) h0, same buf
    _Float16* sB1 = sB0 + 8192;                             // B(t+2) h1
    const int kof1 = (t + 1) * 64, kof2 = (t + 2) * 64;

    half8 a[4][2], b[4][2];

    // ---- half 1: A-lo + ALL B reads; stage A(t+1) (other buf: no hazard) ----
#pragma unroll
    for (int i = 0; i < 4; ++i) {
        a[i][0] = *(const half8*)(Ab + i * 1024 + sl0);
        a[i][1] = *(const half8*)(Ab + i * 1024 + sl1);
    }
#pragma unroll
    for (int j = 0; j < 4; ++j) {
        b[j][0] = *(const half8*)(Bb + j * 1024 + sl0);
        b[j][1] = *(const half8*)(Bb + j * 1024 + sl1);
    }
    if (SA) { STG(ga0 + kof1, sA0); STG(ga1 + kof1, sA1); }
    __builtin_amdgcn_s_setprio(1);
#pragma unroll
    for (int s = 0; s < 2; ++s)
#pragma unroll
        for (int i = 0; i < 4; ++i)
#pragma unroll
            for (int j = 0; j < 4; ++j)
                acc[i][j] = MFMA16(a[i][s], b[j][s], acc[i][j]);
    __builtin_amdgcn_s_setprio(0);
    BAR();   // all waves' B reads complete -> B region safe to overwrite

    // ---- half 2: A-hi reads; stage B(t+2) into current buf B region ----
#pragma unroll
    for (int i = 0; i < 4; ++i) {
        a[i][0] = *(const half8*)(Ab + (4 + i) * 1024 + sl0);
        a[i][1] = *(const half8*)(Ab + (4 + i) * 1024 + sl1);
    }
    if (SB) { STG(gb0 + kof2, sB0); STG(gb1 + kof2, sB1); }
    __builtin_amdgcn_s_setprio(1);
#pragma unroll
    for (int s = 0; s < 2; ++s)
#pragma unroll
        for (int i = 0; i < 4; ++i)
#pragma unroll
            for (int j = 0; j < 4; ++j)
                acc[4 + i][j] = MFMA16(a[i][s], b[j][s], acc[4 + i][j]);
    __builtin_amdgcn_s_setprio(0);
    if (VM == 4) { VMW4(); }
    else if (VM == 0) { VMW0(); }
    BAR();
}

__global__ __launch_bounds__(512, 2) void qkv_gemm8(const _Float16* __restrict__ X,
                                                    const _Float16* __restrict__ W,
                                                    _Float16* __restrict__ qh,
                                                    _Float16* __restrict__ kh,
                                                    _Float16* __restrict__ vt) {
    __shared__ __align__(16) _Float16 smem[65536];   // 128 KiB
    const int tid = threadIdx.x;
    const int lane = tid & 63, wid = tid >> 6;
    const int r = lane & 15, q = lane >> 4;
    const int wm = wid >> 2, wn = wid & 3;

    // bijective XCD swizzle: 936 blocks = 8 XCDs x (13 M-bands x 9 col-blocks)
    const int id = blockIdx.x;
    const int swz = (id & 7) * 117 + (id >> 3);
    const int by = swz / 9, bx = swz - by * 9;
    const int m0b = by * 256, n0b = bx * 256;

    // staging addresses: row = wid*8 + lane/8 (+64 for round 1), pre-swizzled chunk
    const int srow = wid * 8 + (lane >> 3);
    const int sch = (lane & 7) ^ (lane >> 3);
    const _Float16* ga0 = X + (size_t)(m0b + srow) * DIM + sch * 8;
    const _Float16* ga1 = ga0 + (size_t)128 * DIM;
    const _Float16* gb0 = W + (size_t)(n0b + srow) * DIM + sch * 8;
    const _Float16* gb1 = gb0 + (size_t)128 * DIM;
    const int sbase = wid * 512;         // wave-uniform LDS base (elems)

    floatx4 acc[8][4] = {};

    // prologue: tile0 fully + tile1 B halves; wait tile0 (vmcnt(4))
    STG(ga0, smem + sbase);                          // A0 h0
    STG(ga1, smem + 8192 + sbase);                   // A0 h1
    STG(gb0, smem + 16384 + sbase);                  // B0 h0
    STG(gb1, smem + 24576 + sbase);                  // B0 h1
    STG(gb0 + 64, smem + 32768 + 16384 + sbase);     // B1 h0
    STG(gb1 + 64, smem + 32768 + 24576 + sbase);     // B1 h1
    VMW4();                                          // A0,B0 done; B1 in flight
    BAR();

#pragma unroll 2
    for (int t = 0; t < 10; ++t)
        qkv_tile<4, true, true>(t, smem, ga0, ga1, gb0, gb1, sbase, r, q, wm, wn, acc);
    qkv_tile<0, true, false>(10, smem, ga0, ga1, gb0, gb1, sbase, r, q, wm, wn, acc);
    qkv_tile<-1, false, false>(11, smem, ga0, ga1, gb0, gb1, sbase, r, q, wm, wn, acc);

    // ---- epilogue: transpose via LDS, two row-half passes ----
    __syncthreads();
    const int which = bx / 3;                 // 0=q 1=k 2=v
    const int cb = (bx - which * 3) * 256;    // col base within 768-block
    if (which == 2) {
#pragma unroll
        for (int hp = 0; hp < 2; ++hp) {
            if (wm == hp) {
                // T[c][g] pitch 136: c = col, g = row-in-half
#pragma unroll
                for (int i = 0; i < 8; ++i)
#pragma unroll
                    for (int j = 0; j < 4; ++j) {
                        half4 hv;
#pragma unroll
                        for (int rr = 0; rr < 4; ++rr) hv[rr] = (_Float16)acc[i][j][rr];
                        *(half4*)&smem[(wn * 64 + j * 16 + r) * 136 + i * 16 + q * 4] = hv;
                    }
            }
            __syncthreads();
#pragma unroll
            for (int p = 0; p < 8; ++p) {
                int idx = p * 512 + tid;
                int c = idx >> 4, g0 = (idx & 15) * 8;
                int grow = m0b + hp * 128 + g0;
                int b_idx = grow / NPAD, n_idx = grow - b_idx * NPAD;
                int vcol = cb + c;
                int hh = vcol >> 6, d = vcol & 63;
                half8 hv = *(const half8*)&smem[c * 136 + g0];
                *(half8*)&vt[((size_t)(b_idx * NH + hh) * DH + d) * KPAD + n_idx] = hv;
            }
            __syncthreads();
        }
    } else {
        const float scale = (which == 0) ? 0.125f : 1.0f;  // 64^-0.5 folded into q
        _Float16* dst = (which == 0) ? qh : kh;
#pragma unroll
        for (int hp = 0; hp < 2; ++hp) {
            if (wm == hp) {
                // T[g][c] pitch 272 (row stride 16 dwords mod 32 banks: conflict-free)
#pragma unroll
                for (int i = 0; i < 8; ++i)
#pragma unroll
                    for (int j = 0; j < 4; ++j)
#pragma unroll
                        for (int rr = 0; rr < 4; ++rr)
                            smem[(i * 16 + q * 4 + rr) * 272 + wn * 64 + j * 16 + r] =
                                (_Float16)(acc[i][j][rr] * scale);
            }
            __syncthreads();
#pragma unroll
            for (int p = 0; p < 8; ++p) {
                int idx = p * 512 + tid;
                int g = idx >> 5, c0 = (idx & 31) * 8;
                int grow = m0b + hp * 128 + g;
                int b_idx = grow / NPAD, n_idx = grow - b_idx * NPAD;
                int colm = cb + c0;
                int hh = colm >> 6, d0 = colm & 63;
                half8 hv = *(const half8*)&smem[g * 272 + c0];
                *(half8*)&dst[((size_t)(b_idx * NH + hh) * NPAD + n_idx) * DH + d0] = hv;
            }
            __syncthreads();
        }
    }
}

// =====================================================================
// m97-style GEMM core (kept for proj): 128x128 tile, BK=64, swizzled atoms.
// =====================================================================
__device__ __forceinline__ void gemm_core_768(const _Float16* __restrict__ A,
                                              const _Float16* __restrict__ B,
                                              int m0b, int n0b,
                                              _Float16* As, _Float16* Bs,
                                              floatx4 acc[4][4]) {
    const int lane = threadIdx.x & 63;
    const int w = threadIdx.x >> 6;
    const int r = lane & 15, q = lane >> 4;
    const int mo = (w & 1) * 64;                    // wave sub-tile row offset in A
    const int no = (w >> 1) * 64;                   // wave sub-tile row offset in B
    const int srow = w * 32 + (lane >> 3);          // staging row (per chunk +8)
    const int gatom = (lane & 7) ^ (lane >> 3);     // swizzled k-atom this lane fetches
    const int rx = r & 7;

    const _Float16* pa[4];
    const _Float16* pb[4];
#pragma unroll
    for (int c = 0; c < 4; ++c) {
        pa[c] = A + (size_t)(m0b + srow + c * 8) * DIM + gatom * 8;
        pb[c] = B + (size_t)(n0b + srow + c * 8) * DIM + gatom * 8;
    }
    _Float16* ldsA = As + w * 2048;
    _Float16* ldsB = Bs + w * 2048;

    for (int kk = 0; kk < DIM / 64; ++kk) {
#pragma unroll
        for (int c = 0; c < 4; ++c) {
            GLDS16(pa[c], ldsA + c * 512);
            GLDS16(pb[c], ldsB + c * 512);
            pa[c] += 64;
            pb[c] += 64;
        }
        __syncthreads();
#pragma unroll
        for (int s = 0; s < 2; ++s) {
            half8 a[4], b[4];
#pragma unroll
            for (int i = 0; i < 4; ++i)
                a[i] = *(const half8*)&As[((mo + i * 16 + r) * 8 + ((s * 4 + q) ^ rx)) * 8];
#pragma unroll
            for (int j = 0; j < 4; ++j)
                b[j] = *(const half8*)&Bs[((no + j * 16 + r) * 8 + ((s * 4 + q) ^ rx)) * 8];
#pragma unroll
            for (int i = 0; i < 4; ++i)
#pragma unroll
                for (int j = 0; j < 4; ++j)
                    acc[i][j] = MFMA16(a[i], b[j], acc[i][j]);
        }
        __syncthreads();
    }
}

// ---------------- proj GEMM: [25216,768] x [768,768]^T + bias -> fp32 out ----------------
__global__ __launch_bounds__(256) void proj_gemm(const _Float16* __restrict__ A,
                                                 const _Float16* __restrict__ W,
                                                 const float* __restrict__ bias,
                                                 float* __restrict__ out) {
    __shared__ __align__(16) _Float16 As[128 * 64];
    __shared__ __align__(16) _Float16 Bs[128 * 64];
    const int lane = threadIdx.x & 63;
    const int w = threadIdx.x >> 6;
    const int r = lane & 15, q = lane >> 4;

    const int id = blockIdx.x;
    const int xcd = id & 7;
    const int lid = id >> 3;
    const int bx = lid % 6;
    const int by = xcd * 25 + lid / 6;
    if (by >= 197) return;                   // whole block exits: no barrier hazard
    const int m0b = by * 128;
    const int n0b = bx * 128;

    floatx4 acc[4][4] = {};
    gemm_core_768(A, W, m0b, n0b, As, Bs, acc);

    const int m0 = m0b + (w & 1) * 64;
    const int n0 = n0b + (w >> 1) * 64;
#pragma unroll
    for (int i = 0; i < 4; ++i) {
#pragma unroll
        for (int rr = 0; rr < 4; ++rr) {
            size_t grow = m0 + i * 16 + q * 4 + rr;
#pragma unroll
            for (int j = 0; j < 4; ++j) {
                int gcol = n0 + j * 16 + r;
                out[grow * DIM + gcol] = acc[i][j][rr] + bias[gcol];
            }
        }
    }
}

// ---------------- attention: block = one (b,h); K/V staged in LDS ----------
// 13 waves (832 thr), wave w owns q-tile w. K [208][8ch] and V^T [64][32ch]
// staged via global_load_lds with row-low-3-bit XOR chunk swizzle
// (pre-swizzled GLOBAL source, linear LDS dest; reads apply the same XOR).
// All GLDS issues are FULL-WAVE; out-of-range source chunks clamped to 0
// (slots provably never read). Bias = MFMA C-init; exp immediately per nt;
// P stored UNNORMALIZED in half; 1/rowsum folded into final O scale.
__global__ __launch_bounds__(832, 7) void attn_kernel(const _Float16* __restrict__ qh,
                                                      const _Float16* __restrict__ kh,
                                                      const _Float16* __restrict__ vt,
                                                      const _Float16* __restrict__ biasph,
                                                      _Float16* __restrict__ ah) {
    __shared__ __align__(16) _Float16 smem[38016];   // 76 KB: K 26.6K | V 32.8K | P 16.6K
    _Float16* Ks = smem;                  // [208][8 chunks swz]
    _Float16* Vs = smem + 13312;          // [64][32 chunks swz, 28 valid]
    _Float16* Pb = smem + 29696;          // [13][16][40]
    const int tid = threadIdx.x;
    const int w = tid >> 6, lane = tid & 63;
    const int r = lane & 15, q = lane >> 4;
    const int xr = r & 7;
    const int bh = ((blockIdx.x & 7) * 192) + (blockIdx.x >> 3);  // XCD-contiguous
    const int b = bh / NH, h = bh - b * NH;
    const _Float16* Kb = kh + (size_t)bh * NPAD * DH;
    const _Float16* Vtb = vt + (size_t)bh * DH * KPAD;

    // ---- stage K: 1664 slots, 2 exact full-wave rounds; src chunk = pos ^ (row&7)
#pragma unroll
    for (int rd = 0; rd < 2; ++rd) {
        int i = rd * 832 + tid;
        int g = i >> 3;
        int cs = (i & 7) ^ (g & 7);
        GLDS16(Kb + (size_t)g * DH + cs * 8, Ks + (rd * 832 + w * 64) * 8);
    }
    // ---- stage V: 2048 slots (pitch 32); rd=2 guard tid<384 = wave boundary
#pragma unroll
    for (int rd = 0; rd < 3; ++rd) {
        int j = rd * 832 + tid;
        if (j < 2048) {
            int g = j >> 5;
            int cs = (j & 31) ^ (g & 7);
            if (cs >= 28) cs = 0;       // branch-free select; slot never read
            GLDS16(Vtb + (size_t)g * KPAD + cs * 8, Vs + (rd * 832 + w * 64) * 8);
        }
    }
    __syncthreads();   // vmcnt(0) drain + barrier: staged data visible

    // ---- per-wave q-tile (qt = w) ----
    const int rowq = w * 16 + r;
    const _Float16* Qb = qh + (size_t)bh * NPAD * DH;
    half8 aq0 = *(const half8*)(Qb + (size_t)rowq * DH + q * 8);
    half8 aq1 = *(const half8*)(Qb + (size_t)rowq * DH + 32 + q * 8);

    // S = QK^T + bias (C-init), exp immediately -> unnormalized P (half)
    const _Float16* bbase = biasph + (((size_t)h * 13 + w) * 13) * 256 + r * 16 + q * 4;
    half4 pvh[NKT + 1];
    float osum[4] = {0.f, 0.f, 0.f, 0.f};
#pragma unroll
    for (int nt = 0; nt < NKT; ++nt) {
        half4 bv = *(const half4*)(bbase + nt * 256);
        floatx4 acc;
        acc[0] = (float)bv[0]; acc[1] = (float)bv[1];
        acc[2] = (float)bv[2]; acc[3] = (float)bv[3];
        const _Float16* kr = Ks + (nt * 16 + r) * 64;
        half8 b0 = *(const half8*)(kr + (q ^ xr) * 8);
        half8 b1 = *(const half8*)(kr + ((q ^ xr) ^ 4) * 8);
        acc = MFMA16(aq0, b0, acc);
        acc = MFMA16(aq1, b1, acc);
        half4 e4;
#pragma unroll
        for (int rr = 0; rr < 4; ++rr) {
            float e = __expf(acc[rr]);      // pad cols: exp(-30000) == 0 exactly
            osum[rr] += e;
            e4[rr] = (_Float16)e;
        }
        pvh[nt] = e4;
    }
    {
        half4 z = {};
        pvh[NKT] = z;                       // tail slot for kt=6
    }
    // row-sum across the 16 key-lanes (r bits 0..3)
#pragma unroll
    for (int rr = 0; rr < 4; ++rr) {
#pragma unroll
        for (int m = 1; m <= 8; m <<= 1) osum[rr] += __shfl_xor(osum[rr], m, 64);
    }

    // O = P V (P unnormalized), chunked over 7 x 32 keys; P via wave-private LDS
    floatx4 oacc[4] = {};
    _Float16* Pw = Pb + w * 640;
#pragma unroll
    for (int kt = 0; kt < 7; ++kt) {
#pragma unroll
        for (int rr = 0; rr < 4; ++rr) {
            Pw[(q * 4 + rr) * 40 + r] = pvh[kt * 2][rr];
            Pw[(q * 4 + rr) * 40 + 16 + r] = pvh[kt * 2 + 1][rr];
        }
        __asm__ volatile("" ::: "memory");   // keep ds_write -> ds_read order
        half8 ap = *(const half8*)&Pw[r * 40 + q * 8];
        __asm__ volatile("" ::: "memory");   // keep ds_read -> next writes order
#pragma unroll
        for (int dt = 0; dt < 4; ++dt) {
            half8 bv = *(const half8*)(Vs + (dt * 16 + r) * 256 + (((kt * 4 + q) ^ xr) * 8));
            oacc[dt] = MFMA16(ap, bv, oacc[dt]);
        }
    }

    // store (pad rows masked), fold 1/rowsum here
#pragma unroll
    for (int rr = 0; rr < 4; ++rr) {
        int row = w * 16 + q * 4 + rr;
        if (row < NTOK) {
            float inv = 1.0f / osum[rr];
            size_t o = ((size_t)b * NTOK + row) * DIM + h * DH;
#pragma unroll
            for (int dt = 0; dt < 4; ++dt)
                ah[o + dt * 16 + r] = (_Float16)(oacc[dt][rr] * inv);
        }
    }
}

// ---------------- launch ----------------
extern "C" void kernel_launch(void* const* d_in, const int* in_sizes, int n_in,
                              void* d_out, int out_size, void* d_ws, size_t ws_size,
                              hipStream_t stream) {
    const float* x = (const float*)d_in[0];        // [128,197,768]
    const float* qkv_w = (const float*)d_in[1];    // [2304,768]
    const float* proj_w = (const float*)d_in[2];   // [768,768]
    const float* proj_b = (const float*)d_in[3];   // [768]
    const float* table = (const float*)d_in[4];    // [730,12]
    const int* ridx = (const int*)d_in[5];         // [197,197]
    float* out = (float*)d_out;

    char* ws = (char*)d_ws;
    const size_t SZ_XP = (size_t)MP_ROWS * DIM * 2;             // 40.9 MB (padded f16)
    const size_t SZ_WQKV = (size_t)3 * DIM * DIM * 2;           //  3.5 MB
    const size_t SZ_WPROJ = (size_t)DIM * DIM * 2;              //  1.2 MB
    const size_t SZ_QK = (size_t)BATCH * NH * NPAD * DH * 2;    // 40.9 MB each
    const size_t SZ_VT = (size_t)BATCH * NH * DH * KPAD * 2;    // 44.0 MB
    const size_t SZ_BIAS = (size_t)NH * 13 * 13 * 256 * 2;      //  1.0 MB

    _Float16* xh = (_Float16*)(ws + 0);
    _Float16* ah = (_Float16*)(ws + 0);              // aliases xh (x dead after qkv)
    _Float16* wqkvh = (_Float16*)(ws + SZ_XP);
    _Float16* wprojh = (_Float16*)(ws + SZ_XP + SZ_WQKV);
    _Float16* qh = (_Float16*)(ws + SZ_XP + SZ_WQKV + SZ_WPROJ);
    _Float16* kh = (_Float16*)(ws + SZ_XP + SZ_WQKV + SZ_WPROJ + SZ_QK);
    _Float16* vt = (_Float16*)(ws + SZ_XP + SZ_WQKV + SZ_WPROJ + 2 * SZ_QK);
    _Float16* biasph = (_Float16*)(ws + SZ_XP + SZ_WQKV + SZ_WPROJ + 2 * SZ_QK + SZ_VT);
    (void)SZ_BIAS; (void)ws_size; (void)n_in; (void)in_sizes; (void)out_size;

    // fused prep: x pad-convert + weight converts + bias pack + vt pad-col zero
    prep_kernel<<<(PREP_TOT + 255) / 256, 256, 0, stream>>>(
        x, qkv_w, proj_w, table, ridx, xh, wqkvh, wprojh, biasph, vt);
    // qkv gemm: 256^2, 2-barrier/tile schedule, vmcnt(4)
    qkv_gemm8<<<936, 512, 0, stream>>>(xh, wqkvh, qh, kh, vt);
    // attention: one block per (b,h), 13 waves, K/V LDS-staged
    attn_kernel<<<BATCH * NH, 832, 0, stream>>>(qh, kh, vt, biasph, ah);
    // proj gemm (XCD-swizzled, guarded)
    proj_gemm<<<1200, 256, 0, stream>>>(ah, wprojh, proj_b, out);
}

// Round 12
// 392.108 us; speedup vs baseline: 1.0175x; 1.0115x over previous
//
#include <hip/hip_runtime.h>
#include <hip/hip_bf16.h>

// ---------------- types ----------------
typedef _Float16 half8 __attribute__((ext_vector_type(8)));
typedef _Float16 half4 __attribute__((ext_vector_type(4)));
typedef float floatx4 __attribute__((ext_vector_type(4)));

#define MFMA16(a, b, c) __builtin_amdgcn_mfma_f32_16x16x32_f16(a, b, c, 0, 0, 0)
#define GLDS16(gp, lp) __builtin_amdgcn_global_load_lds( \
    (const __attribute__((address_space(1))) void*)(gp), \
    (__attribute__((address_space(3))) void*)(lp), 16, 0, 0)

// Problem constants
#define BATCH 128
#define NTOK 197
#define NPAD 208                    // padded tokens per batch (mult of 16)
#define DIM 768
#define NH 12
#define DH 64
#define M_ROWS (BATCH * NTOK)       // 25216 (compact, for proj)
#define MP_ROWS (BATCH * NPAD)      // 26624 (padded, for qkv)
#define KPAD 224                    // padded key count for PV (7 * 32)
#define NKT 13                      // key tiles of 16 (13*16 = 208)

// prep kernel flat ranges (in half8 chunks / elements)
#define PREP_X (MP_ROWS * (DIM / 8))            // 2,555,904 x-pad chunks
#define PREP_WQ (3 * DIM * DIM / 8)             //   221,184 qkv_w chunks
#define PREP_WP (DIM * DIM / 8)                 //    73,728 proj_w chunks
#define PREP_B (NH * 13 * 13 * 256)             //   519,168 bias elements
#define PREP_VZ (BATCH * NH * DH * 2)           //   196,608 vt pad-col chunks
#define PREP_TOT (PREP_X + PREP_WQ + PREP_WP + PREP_B + PREP_VZ)

// raw barrier / counted waits (no compiler vmcnt(0) drain)
#define BAR() __asm__ volatile("s_barrier" ::: "memory")
#define VMW0() __asm__ volatile("s_waitcnt vmcnt(0)" ::: "memory")

// stage one 128x64 half-tile: 2 x global_load_lds(16B) per thread
#define STG(gp, lp) do { \
    GLDS16((gp), (lp)); \
    GLDS16((gp) + 64 * DIM, (lp) + 4096); } while (0)

// ---------------- fused prep: x pad-convert + weight converts + bias pack ----
__device__ __forceinline__ half8 cvt8(const float* s) {
    float4 v0 = *(const float4*)s;
    float4 v1 = *(const float4*)(s + 4);
    half8 o;
    o[0] = (_Float16)v0.x; o[1] = (_Float16)v0.y;
    o[2] = (_Float16)v0.z; o[3] = (_Float16)v0.w;
    o[4] = (_Float16)v1.x; o[5] = (_Float16)v1.y;
    o[6] = (_Float16)v1.z; o[7] = (_Float16)v1.w;
    return o;
}

__global__ void prep_kernel(const float* __restrict__ x,
                            const float* __restrict__ qkv_w,
                            const float* __restrict__ proj_w,
                            const float* __restrict__ table,
                            const int* __restrict__ ridx,
                            _Float16* __restrict__ xh,
                            _Float16* __restrict__ wqkvh,
                            _Float16* __restrict__ wprojh,
                            _Float16* __restrict__ biasph,
                            _Float16* __restrict__ vt) {
    int idx = blockIdx.x * 256 + threadIdx.x;
    if (idx < PREP_X) {
        // x: [128,197,768] f32 -> [128,208,768] f16 (pad rows = 0)
        int row = idx / (DIM / 8), ch = idx - row * (DIM / 8);
        int b = row / NPAD, n = row - b * NPAD;
        half8 o = {};
        if (n < NTOK) o = cvt8(x + (size_t)(b * NTOK + n) * DIM + ch * 8);
        *(half8*)&xh[(size_t)row * DIM + ch * 8] = o;
        return;
    }
    idx -= PREP_X;
    if (idx < PREP_WQ) {
        *(half8*)&wqkvh[idx * 8] = cvt8(qkv_w + idx * 8);
        return;
    }
    idx -= PREP_WQ;
    if (idx < PREP_WP) {
        *(half8*)&wprojh[idx * 8] = cvt8(proj_w + idx * 8);
        return;
    }
    idx -= PREP_WP;
    if (idx < PREP_B) {
        // biasph[(h*13+qt)*13+nt][r(16)][q(4)][rr(4)]; pad cols = -30000
        int e = idx & 255;
        int r = e >> 4, q = (e >> 2) & 3, rr = e & 3;
        int t = idx >> 8;
        int nt = t % 13; int t2 = t / 13; int qt = t2 % 13; int h = t2 / 13;
        int row = qt * 16 + q * 4 + rr;
        int col = nt * 16 + r;
        float v = -30000.0f;
        if (col < NTOK) {
            int rc = row < NTOK ? row : NTOK - 1;   // clamped rows: value unused
            v = table[ridx[rc * NTOK + col] * NH + h];
        }
        biasph[idx] = (_Float16)v;
        return;
    }
    idx -= PREP_B;
    if (idx < PREP_VZ) {
        // zero vt pad cols 208..223 so attn LDS staging reads defined data
        int row = idx >> 1, c = idx & 1;            // row = bh*64 + d
        half8 z = {};
        *(half8*)&vt[(size_t)row * KPAD + 208 + c * 8] = z;
    }
}

// =====================================================================
// QKV GEMM — 128x256 tile, BK=64, 8 waves (2M x 4N), SINGLE-BUFFER loop,
// 2 blocks/CU. acc[4][4] = 64 VGPR (vs 128 at 256^2) and 48KB loop-LDS
// unlock 2 resident blocks: one block's MFMAs hide the other's staging
// drain (m114 inter-block overlap replaces intra-block pipelining).
// Per K-tile: BAR; stage A(128x64)+B(256x64) via 6 global_load_lds;
// vmcnt(0); BAR; two k-slice phases of {8 ds_read_b128 + 16 MFMA}.
// Read geometry/swizzle identical to the proven round-7 kernel.
// =====================================================================
__global__ __launch_bounds__(512, 4) void qkv_gemm8(const _Float16* __restrict__ X,
                                                    const _Float16* __restrict__ W,
                                                    _Float16* __restrict__ qh,
                                                    _Float16* __restrict__ kh,
                                                    _Float16* __restrict__ vt) {
    // loop uses 24576 halfs (48KB): A [0,8192) = 128x64, B [8192,24576) = 256x64
    // epilogue transpose needs up to 34816 halfs (69.6KB) -> size for that
    __shared__ __align__(16) _Float16 smem[34816];
    const int tid = threadIdx.x;
    const int lane = tid & 63, wid = tid >> 6;
    const int r = lane & 15, q = lane >> 4;
    const int wm = wid >> 2, wn = wid & 3;     // wm: row-half (64), wn: col-quarter (64)

    // bijective XCD swizzle: 1872 blocks = 8 XCDs x 234 (26 M-bands x 9 cols)
    const int id = blockIdx.x;
    const int swz = (id & 7) * 234 + (id >> 3);
    const int by = swz / 9, bx = swz - by * 9;
    const int m0b = by * 128, n0b = bx * 256;

    // staging: row = wid*8 + lane/8 (+64 via STG pair), pre-swizzled chunk
    const int srow = wid * 8 + (lane >> 3);
    const int sch = (lane & 7) ^ (lane >> 3);
    const _Float16* ga0 = X + (size_t)(m0b + srow) * DIM + sch * 8;
    const _Float16* gb0 = W + (size_t)(n0b + srow) * DIM + sch * 8;
    const _Float16* gb1 = gb0 + (size_t)128 * DIM;
    const int sbase = wid * 512;               // wave-uniform LDS base (elems)

    const int r7 = r & 7;
    const int sl0 = (q ^ r7) * 8;              // k-slice 0 swizzled slot
    const int sl1 = sl0 ^ 32;                  // k-slice 1
    const _Float16* Ab = smem + wm * 4096 + r * 64;
    const _Float16* Bb = smem + 8192 + wn * 4096 + r * 64;

    floatx4 acc[4][4] = {};

    for (int t = 0; t < 12; ++t) {
        BAR();                                  // prior tile's reads all consumed
        STG(ga0, smem + sbase);                 // A rows 0..127
        STG(gb0, smem + 8192 + sbase);          // B rows 0..127
        STG(gb1, smem + 16384 + sbase);         // B rows 128..255
        ga0 += 64; gb0 += 64; gb1 += 64;
        VMW0();
        BAR();
        // slice 0
        {
            half8 a[4], b[4];
#pragma unroll
            for (int i = 0; i < 4; ++i) a[i] = *(const half8*)(Ab + i * 1024 + sl0);
#pragma unroll
            for (int j = 0; j < 4; ++j) b[j] = *(const half8*)(Bb + j * 1024 + sl0);
            __builtin_amdgcn_s_setprio(1);
#pragma unroll
            for (int i = 0; i < 4; ++i)
#pragma unroll
                for (int j = 0; j < 4; ++j)
                    acc[i][j] = MFMA16(a[i], b[j], acc[i][j]);
            __builtin_amdgcn_s_setprio(0);
        }
        // slice 1
        {
            half8 a[4], b[4];
#pragma unroll
            for (int i = 0; i < 4; ++i) a[i] = *(const half8*)(Ab + i * 1024 + sl1);
#pragma unroll
            for (int j = 0; j < 4; ++j) b[j] = *(const half8*)(Bb + j * 1024 + sl1);
            __builtin_amdgcn_s_setprio(1);
#pragma unroll
            for (int i = 0; i < 4; ++i)
#pragma unroll
                for (int j = 0; j < 4; ++j)
                    acc[i][j] = MFMA16(a[i], b[j], acc[i][j]);
            __builtin_amdgcn_s_setprio(0);
        }
    }

    // ---- epilogue: transpose via LDS, single pass (128-row tile) ----
    __syncthreads();
    const int which = bx / 3;                 // 0=q 1=k 2=v
    const int cb = (bx - which * 3) * 256;    // col base within 768-block
    if (which == 2) {
        // T[c][g] pitch 136: c = col (256), g = row (128)
#pragma unroll
        for (int i = 0; i < 4; ++i)
#pragma unroll
            for (int j = 0; j < 4; ++j) {
                half4 hv;
#pragma unroll
                for (int rr = 0; rr < 4; ++rr) hv[rr] = (_Float16)acc[i][j][rr];
                *(half4*)&smem[(wn * 64 + j * 16 + r) * 136 + wm * 64 + i * 16 + q * 4] = hv;
            }
        __syncthreads();
#pragma unroll
        for (int p = 0; p < 8; ++p) {
            int idx = p * 512 + tid;
            int c = idx >> 4, g0 = (idx & 15) * 8;
            int grow = m0b + g0;
            int b_idx = grow / NPAD, n_idx = grow - b_idx * NPAD;
            int vcol = cb + c;
            int hh = vcol >> 6, d = vcol & 63;
            half8 hv = *(const half8*)&smem[c * 136 + g0];
            *(half8*)&vt[((size_t)(b_idx * NH + hh) * DH + d) * KPAD + n_idx] = hv;
        }
    } else {
        const float scale = (which == 0) ? 0.125f : 1.0f;  // 64^-0.5 folded into q
        _Float16* dst = (which == 0) ? qh : kh;
        // T[g][c] pitch 272 (row stride 16 dwords mod 32 banks: conflict-free)
#pragma unroll
        for (int i = 0; i < 4; ++i)
#pragma unroll
            for (int j = 0; j < 4; ++j)
#pragma unroll
                for (int rr = 0; rr < 4; ++rr)
                    smem[(wm * 64 + i * 16 + q * 4 + rr) * 272 + wn * 64 + j * 16 + r] =
                        (_Float16)(acc[i][j][rr] * scale);
        __syncthreads();
#pragma unroll
        for (int p = 0; p < 8; ++p) {
            int idx = p * 512 + tid;
            int g = idx >> 5, c0 = (idx & 31) * 8;
            int grow = m0b + g;
            int b_idx = grow / NPAD, n_idx = grow - b_idx * NPAD;
            int colm = cb + c0;
            int hh = colm >> 6, d0 = colm & 63;
            half8 hv = *(const half8*)&smem[g * 272 + c0];
            *(half8*)&dst[((size_t)(b_idx * NH + hh) * NPAD + n_idx) * DH + d0] = hv;
        }
    }
}

// =====================================================================
// m97-style GEMM core (kept for proj): 128x128 tile, BK=64, swizzled atoms.
// =====================================================================
__device__ __forceinline__ void gemm_core_768(const _Float16* __restrict__ A,
                                              const _Float16* __restrict__ B,
                                              int m0b, int n0b,
                                              _Float16* As, _Float16* Bs,
                                              floatx4 acc[4][4]) {
    const int lane = threadIdx.x & 63;
    const int w = threadIdx.x >> 6;
    const int r = lane & 15, q = lane >> 4;
    const int mo = (w & 1) * 64;                    // wave sub-tile row offset in A
    const int no = (w >> 1) * 64;                   // wave sub-tile row offset in B
    const int srow = w * 32 + (lane >> 3);          // staging row (per chunk +8)
    const int gatom = (lane & 7) ^ (lane >> 3);     // swizzled k-atom this lane fetches
    const int rx = r & 7;

    const _Float16* pa[4];
    const _Float16* pb[4];
#pragma unroll
    for (int c = 0; c < 4; ++c) {
        pa[c] = A + (size_t)(m0b + srow + c * 8) * DIM + gatom * 8;
        pb[c] = B + (size_t)(n0b + srow + c * 8) * DIM + gatom * 8;
    }
    _Float16* ldsA = As + w * 2048;
    _Float16* ldsB = Bs + w * 2048;

    for (int kk = 0; kk < DIM / 64; ++kk) {
#pragma unroll
        for (int c = 0; c < 4; ++c) {
            GLDS16(pa[c], ldsA + c * 512);
            GLDS16(pb[c], ldsB + c * 512);
            pa[c] += 64;
            pb[c] += 64;
        }
        __syncthreads();
#pragma unroll
        for (int s = 0; s < 2; ++s) {
            half8 a[4], b[4];
#pragma unroll
            for (int i = 0; i < 4; ++i)
                a[i] = *(const half8*)&As[((mo + i * 16 + r) * 8 + ((s * 4 + q) ^ rx)) * 8];
#pragma unroll
            for (int j = 0; j < 4; ++j)
                b[j] = *(const half8*)&Bs[((no + j * 16 + r) * 8 + ((s * 4 + q) ^ rx)) * 8];
#pragma unroll
            for (int i = 0; i < 4; ++i)
#pragma unroll
                for (int j = 0; j < 4; ++j)
                    acc[i][j] = MFMA16(a[i], b[j], acc[i][j]);
        }
        __syncthreads();
    }
}

// ---------------- proj GEMM: [25216,768] x [768,768]^T + bias -> fp32 out ----------------
__global__ __launch_bounds__(256) void proj_gemm(const _Float16* __restrict__ A,
                                                 const _Float16* __restrict__ W,
                                                 const float* __restrict__ bias,
                                                 float* __restrict__ out) {
    __shared__ __align__(16) _Float16 As[128 * 64];
    __shared__ __align__(16) _Float16 Bs[128 * 64];
    const int lane = threadIdx.x & 63;
    const int w = threadIdx.x >> 6;
    const int r = lane & 15, q = lane >> 4;

    const int id = blockIdx.x;
    const int xcd = id & 7;
    const int lid = id >> 3;
    const int bx = lid % 6;
    const int by = xcd * 25 + lid / 6;
    if (by >= 197) return;                   // whole block exits: no barrier hazard
    const int m0b = by * 128;
    const int n0b = bx * 128;

    floatx4 acc[4][4] = {};
    gemm_core_768(A, W, m0b, n0b, As, Bs, acc);

    const int m0 = m0b + (w & 1) * 64;
    const int n0 = n0b + (w >> 1) * 64;
#pragma unroll
    for (int i = 0; i < 4; ++i) {
#pragma unroll
        for (int rr = 0; rr < 4; ++rr) {
            size_t grow = m0 + i * 16 + q * 4 + rr;
#pragma unroll
            for (int j = 0; j < 4; ++j) {
                int gcol = n0 + j * 16 + r;
                out[grow * DIM + gcol] = acc[i][j][rr] + bias[gcol];
            }
        }
    }
}

// ---------------- attention: block = one (b,h); K/V staged in LDS ----------
// 13 waves (832 thr), wave w owns q-tile w. K [208][8ch] and V^T [64][32ch]
// staged via global_load_lds with row-low-3-bit XOR chunk swizzle
// (pre-swizzled GLOBAL source, linear LDS dest; reads apply the same XOR).
// All GLDS issues are FULL-WAVE; out-of-range source chunks clamped to 0
// (slots provably never read). Bias = MFMA C-init; exp immediately per nt;
// P stored UNNORMALIZED in half; 1/rowsum folded into final O scale.
__global__ __launch_bounds__(832, 7) void attn_kernel(const _Float16* __restrict__ qh,
                                                      const _Float16* __restrict__ kh,
                                                      const _Float16* __restrict__ vt,
                                                      const _Float16* __restrict__ biasph,
                                                      _Float16* __restrict__ ah) {
    __shared__ __align__(16) _Float16 smem[38016];   // 76 KB: K 26.6K | V 32.8K | P 16.6K
    _Float16* Ks = smem;                  // [208][8 chunks swz]
    _Float16* Vs = smem + 13312;          // [64][32 chunks swz, 28 valid]
    _Float16* Pb = smem + 29696;          // [13][16][40]
    const int tid = threadIdx.x;
    const int w = tid >> 6, lane = tid & 63;
    const int r = lane & 15, q = lane >> 4;
    const int xr = r & 7;
    const int bh = ((blockIdx.x & 7) * 192) + (blockIdx.x >> 3);  // XCD-contiguous
    const int b = bh / NH, h = bh - b * NH;
    const _Float16* Kb = kh + (size_t)bh * NPAD * DH;
    const _Float16* Vtb = vt + (size_t)bh * DH * KPAD;

    // ---- stage K: 1664 slots, 2 exact full-wave rounds; src chunk = pos ^ (row&7)
#pragma unroll
    for (int rd = 0; rd < 2; ++rd) {
        int i = rd * 832 + tid;
        int g = i >> 3;
        int cs = (i & 7) ^ (g & 7);
        GLDS16(Kb + (size_t)g * DH + cs * 8, Ks + (rd * 832 + w * 64) * 8);
    }
    // ---- stage V: 2048 slots (pitch 32); rd=2 guard tid<384 = wave boundary
#pragma unroll
    for (int rd = 0; rd < 3; ++rd) {
        int j = rd * 832 + tid;
        if (j < 2048) {
            int g = j >> 5;
            int cs = (j & 31) ^ (g & 7);
            if (cs >= 28) cs = 0;       // branch-free select; slot never read
            GLDS16(Vtb + (size_t)g * KPAD + cs * 8, Vs + (rd * 832 + w * 64) * 8);
        }
    }
    __syncthreads();   // vmcnt(0) drain + barrier: staged data visible

    // ---- per-wave q-tile (qt = w) ----
    const int rowq = w * 16 + r;
    const _Float16* Qb = qh + (size_t)bh * NPAD * DH;
    half8 aq0 = *(const half8*)(Qb + (size_t)rowq * DH + q * 8);
    half8 aq1 = *(const half8*)(Qb + (size_t)rowq * DH + 32 + q * 8);

    // S = QK^T + bias (C-init), exp immediately -> unnormalized P (half)
    const _Float16* bbase = biasph + (((size_t)h * 13 + w) * 13) * 256 + r * 16 + q * 4;
    half4 pvh[NKT + 1];
    float osum[4] = {0.f, 0.f, 0.f, 0.f};
#pragma unroll
    for (int nt = 0; nt < NKT; ++nt) {
        half4 bv = *(const half4*)(bbase + nt * 256);
        floatx4 acc;
        acc[0] = (float)bv[0]; acc[1] = (float)bv[1];
        acc[2] = (float)bv[2]; acc[3] = (float)bv[3];
        const _Float16* kr = Ks + (nt * 16 + r) * 64;
        half8 b0 = *(const half8*)(kr + (q ^ xr) * 8);
        half8 b1 = *(const half8*)(kr + ((q ^ xr) ^ 4) * 8);
        acc = MFMA16(aq0, b0, acc);
        acc = MFMA16(aq1, b1, acc);
        half4 e4;
#pragma unroll
        for (int rr = 0; rr < 4; ++rr) {
            float e = __expf(acc[rr]);      // pad cols: exp(-30000) == 0 exactly
            osum[rr] += e;
            e4[rr] = (_Float16)e;
        }
        pvh[nt] = e4;
    }
    {
        half4 z = {};
        pvh[NKT] = z;                       // tail slot for kt=6
    }
    // row-sum across the 16 key-lanes (r bits 0..3)
#pragma unroll
    for (int rr = 0; rr < 4; ++rr) {
#pragma unroll
        for (int m = 1; m <= 8; m <<= 1) osum[rr] += __shfl_xor(osum[rr], m, 64);
    }

    // O = P V (P unnormalized), chunked over 7 x 32 keys; P via wave-private LDS
    floatx4 oacc[4] = {};
    _Float16* Pw = Pb + w * 640;
#pragma unroll
    for (int kt = 0; kt < 7; ++kt) {
#pragma unroll
        for (int rr = 0; rr < 4; ++rr) {
            Pw[(q * 4 + rr) * 40 + r] = pvh[kt * 2][rr];
            Pw[(q * 4 + rr) * 40 + 16 + r] = pvh[kt * 2 + 1][rr];
        }
        __asm__ volatile("" ::: "memory");   // keep ds_write -> ds_read order
        half8 ap = *(const half8*)&Pw[r * 40 + q * 8];
        __asm__ volatile("" ::: "memory");   // keep ds_read -> next writes order
#pragma unroll
        for (int dt = 0; dt < 4; ++dt) {
            half8 bv = *(const half8*)(Vs + (dt * 16 + r) * 256 + (((kt * 4 + q) ^ xr) * 8));
            oacc[dt] = MFMA16(ap, bv, oacc[dt]);
        }
    }

    // store (pad rows masked), fold 1/rowsum here
#pragma unroll
    for (int rr = 0; rr < 4; ++rr) {
        int row = w * 16 + q * 4 + rr;
        if (row < NTOK) {
            float inv = 1.0f / osum[rr];
            size_t o = ((size_t)b * NTOK + row) * DIM + h * DH;
#pragma unroll
            for (int dt = 0; dt < 4; ++dt)
                ah[o + dt * 16 + r] = (_Float16)(oacc[dt][rr] * inv);
        }
    }
}

// ---------------- launch ----------------
extern "C" void kernel_launch(void* const* d_in, const int* in_sizes, int n_in,
                              void* d_out, int out_size, void* d_ws, size_t ws_size,
                              hipStream_t stream) {
    const float* x = (const float*)d_in[0];        // [128,197,768]
    const float* qkv_w = (const float*)d_in[1];    // [2304,768]
    const float* proj_w = (const float*)d_in[2];   // [768,768]
    const float* proj_b = (const float*)d_in[3];   // [768]
    const float* table = (const float*)d_in[4];    // [730,12]
    const int* ridx = (const int*)d_in[5];         // [197,197]
    float* out = (float*)d_out;

    char* ws = (char*)d_ws;
    const size_t SZ_XP = (size_t)MP_ROWS * DIM * 2;             // 40.9 MB (padded f16)
    const size_t SZ_WQKV = (size_t)3 * DIM * DIM * 2;           //  3.5 MB
    const size_t SZ_WPROJ = (size_t)DIM * DIM * 2;              //  1.2 MB
    const size_t SZ_QK = (size_t)BATCH * NH * NPAD * DH * 2;    // 40.9 MB each
    const size_t SZ_VT = (size_t)BATCH * NH * DH * KPAD * 2;    // 44.0 MB
    const size_t SZ_BIAS = (size_t)NH * 13 * 13 * 256 * 2;      //  1.0 MB

    _Float16* xh = (_Float16*)(ws + 0);
    _Float16* ah = (_Float16*)(ws + 0);              // aliases xh (x dead after qkv)
    _Float16* wqkvh = (_Float16*)(ws + SZ_XP);
    _Float16* wprojh = (_Float16*)(ws + SZ_XP + SZ_WQKV);
    _Float16* qh = (_Float16*)(ws + SZ_XP + SZ_WQKV + SZ_WPROJ);
    _Float16* kh = (_Float16*)(ws + SZ_XP + SZ_WQKV + SZ_WPROJ + SZ_QK);
    _Float16* vt = (_Float16*)(ws + SZ_XP + SZ_WQKV + SZ_WPROJ + 2 * SZ_QK);
    _Float16* biasph = (_Float16*)(ws + SZ_XP + SZ_WQKV + SZ_WPROJ + 2 * SZ_QK + SZ_VT);
    (void)SZ_BIAS; (void)ws_size; (void)n_in; (void)in_sizes; (void)out_size;

    // fused prep: x pad-convert + weight converts + bias pack + vt pad-col zero
    prep_kernel<<<(PREP_TOT + 255) / 256, 256, 0, stream>>>(
        x, qkv_w, proj_w, table, ridx, xh, wqkvh, wprojh, biasph, vt);
    // qkv gemm: 128x256 single-buffer tiles, 2 blocks/CU, 1872 blocks
    qkv_gemm8<<<1872, 512, 0, stream>>>(xh, wqkvh, qh, kh, vt);
    // attention: one block per (b,h), 13 waves, K/V LDS-staged
    attn_kernel<<<BATCH * NH, 832, 0, stream>>>(qh, kh, vt, biasph, ah);
    // proj gemm (XCD-swizzled, guarded)
    proj_gemm<<<1200, 256, 0, stream>>>(ah, wprojh, proj_b, out);
}

// Round 13
// 380.253 us; speedup vs baseline: 1.0492x; 1.0312x over previous
//
#include <hip/hip_runtime.h>
#include <hip/hip_bf16.h>

// ---------------- types ----------------
typedef _Float16 half8 __attribute__((ext_vector_type(8)));
typedef _Float16 half4 __attribute__((ext_vector_type(4)));
typedef float floatx4 __attribute__((ext_vector_type(4)));

#define MFMA16(a, b, c) __builtin_amdgcn_mfma_f32_16x16x32_f16(a, b, c, 0, 0, 0)
#define GLDS16(gp, lp) __builtin_amdgcn_global_load_lds( \
    (const __attribute__((address_space(1))) void*)(gp), \
    (__attribute__((address_space(3))) void*)(lp), 16, 0, 0)

// Problem constants
#define BATCH 128
#define NTOK 197
#define NPAD 208                    // padded tokens per batch (mult of 16)
#define DIM 768
#define NH 12
#define DH 64
#define M_ROWS (BATCH * NTOK)       // 25216 (compact, for proj)
#define MP_ROWS (BATCH * NPAD)      // 26624 (padded, for qkv)
#define KPAD 224                    // padded key count for PV (7 * 32)
#define NKT 13                      // key tiles of 16 (13*16 = 208)

// prep kernel flat ranges (in half8 chunks / elements)
#define PREP_X (MP_ROWS * (DIM / 8))            // 2,555,904 x-pad chunks
#define PREP_WQ (3 * DIM * DIM / 8)             //   221,184 qkv_w chunks
#define PREP_WP (DIM * DIM / 8)                 //    73,728 proj_w chunks
#define PREP_B (NH * 13 * 13 * 256)             //   519,168 bias elements
#define PREP_VZ (BATCH * NH * DH * 2)           //   196,608 vt pad-col chunks
#define PREP_TOT (PREP_X + PREP_WQ + PREP_WP + PREP_B + PREP_VZ)

// raw barrier / counted waits (no compiler vmcnt(0) drain)
#define BAR() __asm__ volatile("s_barrier" ::: "memory")
#define VMW0() __asm__ volatile("s_waitcnt vmcnt(0)" ::: "memory")

// stage one 128x64 half-tile: 2 x global_load_lds(16B) per thread
#define STG(gp, lp) do { \
    GLDS16((gp), (lp)); \
    GLDS16((gp) + 64 * DIM, (lp) + 4096); } while (0)

// ---------------- fused prep: x pad-convert + weight converts + bias pack ----
__device__ __forceinline__ half8 cvt8(const float* s) {
    float4 v0 = *(const float4*)s;
    float4 v1 = *(const float4*)(s + 4);
    half8 o;
    o[0] = (_Float16)v0.x; o[1] = (_Float16)v0.y;
    o[2] = (_Float16)v0.z; o[3] = (_Float16)v0.w;
    o[4] = (_Float16)v1.x; o[5] = (_Float16)v1.y;
    o[6] = (_Float16)v1.z; o[7] = (_Float16)v1.w;
    return o;
}

__global__ void prep_kernel(const float* __restrict__ x,
                            const float* __restrict__ qkv_w,
                            const float* __restrict__ proj_w,
                            const float* __restrict__ table,
                            const int* __restrict__ ridx,
                            _Float16* __restrict__ xh,
                            _Float16* __restrict__ wqkvh,
                            _Float16* __restrict__ wprojh,
                            _Float16* __restrict__ biasph,
                            _Float16* __restrict__ vt) {
    int idx = blockIdx.x * 256 + threadIdx.x;
    if (idx < PREP_X) {
        // x: [128,197,768] f32 -> [128,208,768] f16 (pad rows = 0)
        int row = idx / (DIM / 8), ch = idx - row * (DIM / 8);
        int b = row / NPAD, n = row - b * NPAD;
        half8 o = {};
        if (n < NTOK) o = cvt8(x + (size_t)(b * NTOK + n) * DIM + ch * 8);
        *(half8*)&xh[(size_t)row * DIM + ch * 8] = o;
        return;
    }
    idx -= PREP_X;
    if (idx < PREP_WQ) {
        *(half8*)&wqkvh[idx * 8] = cvt8(qkv_w + idx * 8);
        return;
    }
    idx -= PREP_WQ;
    if (idx < PREP_WP) {
        *(half8*)&wprojh[idx * 8] = cvt8(proj_w + idx * 8);
        return;
    }
    idx -= PREP_WP;
    if (idx < PREP_B) {
        // biasph[(h*13+qt)*13+nt][r(16)][q(4)][rr(4)]; pad cols = -30000
        int e = idx & 255;
        int r = e >> 4, q = (e >> 2) & 3, rr = e & 3;
        int t = idx >> 8;
        int nt = t % 13; int t2 = t / 13; int qt = t2 % 13; int h = t2 / 13;
        int row = qt * 16 + q * 4 + rr;
        int col = nt * 16 + r;
        float v = -30000.0f;
        if (col < NTOK) {
            int rc = row < NTOK ? row : NTOK - 1;   // clamped rows: value unused
            v = table[ridx[rc * NTOK + col] * NH + h];
        }
        biasph[idx] = (_Float16)v;
        return;
    }
    idx -= PREP_B;
    if (idx < PREP_VZ) {
        // zero vt pad cols 208..223 so attn LDS staging reads defined data
        int row = idx >> 1, c = idx & 1;            // row = bh*64 + d
        half8 z = {};
        *(half8*)&vt[(size_t)row * KPAD + 208 + c * 8] = z;
    }
}

// =====================================================================
// QKV GEMM — 128x256 tile, BK=64, 8 waves (2M x 4N), SINGLE-BUFFER loop,
// 2 blocks/CU. acc[4][4] = 64 VGPR and 48KB loop-LDS unlock 2 resident
// blocks: one block's MFMAs hide the other's staging drain (m114).
// =====================================================================
__global__ __launch_bounds__(512, 4) void qkv_gemm8(const _Float16* __restrict__ X,
                                                    const _Float16* __restrict__ W,
                                                    _Float16* __restrict__ qh,
                                                    _Float16* __restrict__ kh,
                                                    _Float16* __restrict__ vt) {
    // loop uses 24576 halfs (48KB): A [0,8192) = 128x64, B [8192,24576) = 256x64
    // epilogue transpose needs up to 34816 halfs (69.6KB) -> size for that
    __shared__ __align__(16) _Float16 smem[34816];
    const int tid = threadIdx.x;
    const int lane = tid & 63, wid = tid >> 6;
    const int r = lane & 15, q = lane >> 4;
    const int wm = wid >> 2, wn = wid & 3;     // wm: row-half (64), wn: col-quarter (64)

    // bijective XCD swizzle: 1872 blocks = 8 XCDs x 234 (26 M-bands x 9 cols)
    const int id = blockIdx.x;
    const int swz = (id & 7) * 234 + (id >> 3);
    const int by = swz / 9, bx = swz - by * 9;
    const int m0b = by * 128, n0b = bx * 256;

    // staging: row = wid*8 + lane/8 (+64 via STG pair), pre-swizzled chunk
    const int srow = wid * 8 + (lane >> 3);
    const int sch = (lane & 7) ^ (lane >> 3);
    const _Float16* ga0 = X + (size_t)(m0b + srow) * DIM + sch * 8;
    const _Float16* gb0 = W + (size_t)(n0b + srow) * DIM + sch * 8;
    const _Float16* gb1 = gb0 + (size_t)128 * DIM;
    const int sbase = wid * 512;               // wave-uniform LDS base (elems)

    const int r7 = r & 7;
    const int sl0 = (q ^ r7) * 8;              // k-slice 0 swizzled slot
    const int sl1 = sl0 ^ 32;                  // k-slice 1
    const _Float16* Ab = smem + wm * 4096 + r * 64;
    const _Float16* Bb = smem + 8192 + wn * 4096 + r * 64;

    floatx4 acc[4][4] = {};

    for (int t = 0; t < 12; ++t) {
        BAR();                                  // prior tile's reads all consumed
        STG(ga0, smem + sbase);                 // A rows 0..127
        STG(gb0, smem + 8192 + sbase);          // B rows 0..127
        STG(gb1, smem + 16384 + sbase);         // B rows 128..255
        ga0 += 64; gb0 += 64; gb1 += 64;
        VMW0();
        BAR();
        // slice 0
        {
            half8 a[4], b[4];
#pragma unroll
            for (int i = 0; i < 4; ++i) a[i] = *(const half8*)(Ab + i * 1024 + sl0);
#pragma unroll
            for (int j = 0; j < 4; ++j) b[j] = *(const half8*)(Bb + j * 1024 + sl0);
            __builtin_amdgcn_s_setprio(1);
#pragma unroll
            for (int i = 0; i < 4; ++i)
#pragma unroll
                for (int j = 0; j < 4; ++j)
                    acc[i][j] = MFMA16(a[i], b[j], acc[i][j]);
            __builtin_amdgcn_s_setprio(0);
        }
        // slice 1
        {
            half8 a[4], b[4];
#pragma unroll
            for (int i = 0; i < 4; ++i) a[i] = *(const half8*)(Ab + i * 1024 + sl1);
#pragma unroll
            for (int j = 0; j < 4; ++j) b[j] = *(const half8*)(Bb + j * 1024 + sl1);
            __builtin_amdgcn_s_setprio(1);
#pragma unroll
            for (int i = 0; i < 4; ++i)
#pragma unroll
                for (int j = 0; j < 4; ++j)
                    acc[i][j] = MFMA16(a[i], b[j], acc[i][j]);
            __builtin_amdgcn_s_setprio(0);
        }
    }

    // ---- epilogue: transpose via LDS, single pass (128-row tile) ----
    __syncthreads();
    const int which = bx / 3;                 // 0=q 1=k 2=v
    const int cb = (bx - which * 3) * 256;    // col base within 768-block
    if (which == 2) {
        // T[c][g] pitch 136: c = col (256), g = row (128)
#pragma unroll
        for (int i = 0; i < 4; ++i)
#pragma unroll
            for (int j = 0; j < 4; ++j) {
                half4 hv;
#pragma unroll
                for (int rr = 0; rr < 4; ++rr) hv[rr] = (_Float16)acc[i][j][rr];
                *(half4*)&smem[(wn * 64 + j * 16 + r) * 136 + wm * 64 + i * 16 + q * 4] = hv;
            }
        __syncthreads();
#pragma unroll
        for (int p = 0; p < 8; ++p) {
            int idx = p * 512 + tid;
            int c = idx >> 4, g0 = (idx & 15) * 8;
            int grow = m0b + g0;
            int b_idx = grow / NPAD, n_idx = grow - b_idx * NPAD;
            int vcol = cb + c;
            int hh = vcol >> 6, d = vcol & 63;
            half8 hv = *(const half8*)&smem[c * 136 + g0];
            *(half8*)&vt[((size_t)(b_idx * NH + hh) * DH + d) * KPAD + n_idx] = hv;
        }
    } else {
        const float scale = (which == 0) ? 0.125f : 1.0f;  // 64^-0.5 folded into q
        _Float16* dst = (which == 0) ? qh : kh;
        // T[g][c] pitch 272 (row stride 16 dwords mod 32 banks: conflict-free)
#pragma unroll
        for (int i = 0; i < 4; ++i)
#pragma unroll
            for (int j = 0; j < 4; ++j)
#pragma unroll
                for (int rr = 0; rr < 4; ++rr)
                    smem[(wm * 64 + i * 16 + q * 4 + rr) * 272 + wn * 64 + j * 16 + r] =
                        (_Float16)(acc[i][j][rr] * scale);
        __syncthreads();
#pragma unroll
        for (int p = 0; p < 8; ++p) {
            int idx = p * 512 + tid;
            int g = idx >> 5, c0 = (idx & 31) * 8;
            int grow = m0b + g;
            int b_idx = grow / NPAD, n_idx = grow - b_idx * NPAD;
            int colm = cb + c0;
            int hh = colm >> 6, d0 = colm & 63;
            half8 hv = *(const half8*)&smem[g * 272 + c0];
            *(half8*)&dst[((size_t)(b_idx * NH + hh) * NPAD + n_idx) * DH + d0] = hv;
        }
    }
}

// =====================================================================
// m97-style GEMM core (kept for proj): 128x128 tile, BK=64, swizzled atoms.
// =====================================================================
__device__ __forceinline__ void gemm_core_768(const _Float16* __restrict__ A,
                                              const _Float16* __restrict__ B,
                                              int m0b, int n0b,
                                              _Float16* As, _Float16* Bs,
                                              floatx4 acc[4][4]) {
    const int lane = threadIdx.x & 63;
    const int w = threadIdx.x >> 6;
    const int r = lane & 15, q = lane >> 4;
    const int mo = (w & 1) * 64;                    // wave sub-tile row offset in A
    const int no = (w >> 1) * 64;                   // wave sub-tile row offset in B
    const int srow = w * 32 + (lane >> 3);          // staging row (per chunk +8)
    const int gatom = (lane & 7) ^ (lane >> 3);     // swizzled k-atom this lane fetches
    const int rx = r & 7;

    const _Float16* pa[4];
    const _Float16* pb[4];
#pragma unroll
    for (int c = 0; c < 4; ++c) {
        pa[c] = A + (size_t)(m0b + srow + c * 8) * DIM + gatom * 8;
        pb[c] = B + (size_t)(n0b + srow + c * 8) * DIM + gatom * 8;
    }
    _Float16* ldsA = As + w * 2048;
    _Float16* ldsB = Bs + w * 2048;

    for (int kk = 0; kk < DIM / 64; ++kk) {
#pragma unroll
        for (int c = 0; c < 4; ++c) {
            GLDS16(pa[c], ldsA + c * 512);
            GLDS16(pb[c], ldsB + c * 512);
            pa[c] += 64;
            pb[c] += 64;
        }
        __syncthreads();
#pragma unroll
        for (int s = 0; s < 2; ++s) {
            half8 a[4], b[4];
#pragma unroll
            for (int i = 0; i < 4; ++i)
                a[i] = *(const half8*)&As[((mo + i * 16 + r) * 8 + ((s * 4 + q) ^ rx)) * 8];
#pragma unroll
            for (int j = 0; j < 4; ++j)
                b[j] = *(const half8*)&Bs[((no + j * 16 + r) * 8 + ((s * 4 + q) ^ rx)) * 8];
#pragma unroll
            for (int i = 0; i < 4; ++i)
#pragma unroll
                for (int j = 0; j < 4; ++j)
                    acc[i][j] = MFMA16(a[i], b[j], acc[i][j]);
        }
        __syncthreads();
    }
}

// ---------------- proj GEMM: [25216,768] x [768,768]^T + bias -> fp32 out ----------------
__global__ __launch_bounds__(256) void proj_gemm(const _Float16* __restrict__ A,
                                                 const _Float16* __restrict__ W,
                                                 const float* __restrict__ bias,
                                                 float* __restrict__ out) {
    __shared__ __align__(16) _Float16 As[128 * 64];
    __shared__ __align__(16) _Float16 Bs[128 * 64];
    const int lane = threadIdx.x & 63;
    const int w = threadIdx.x >> 6;
    const int r = lane & 15, q = lane >> 4;

    const int id = blockIdx.x;
    const int xcd = id & 7;
    const int lid = id >> 3;
    const int bx = lid % 6;
    const int by = xcd * 25 + lid / 6;
    if (by >= 197) return;                   // whole block exits: no barrier hazard
    const int m0b = by * 128;
    const int n0b = bx * 128;

    floatx4 acc[4][4] = {};
    gemm_core_768(A, W, m0b, n0b, As, Bs, acc);

    const int m0 = m0b + (w & 1) * 64;
    const int n0 = n0b + (w >> 1) * 64;
#pragma unroll
    for (int i = 0; i < 4; ++i) {
#pragma unroll
        for (int rr = 0; rr < 4; ++rr) {
            size_t grow = m0 + i * 16 + q * 4 + rr;
#pragma unroll
            for (int j = 0; j < 4; ++j) {
                int gcol = n0 + j * 16 + r;
                out[grow * DIM + gcol] = acc[i][j][rr] + bias[gcol];
            }
        }
    }
}

// ---------------- attention: block = one (b,h); K/V staged in LDS ----------
// 13 waves (832 thr), wave w owns q-tile w. K [208][8ch] and V^T [64][32ch]
// staged via global_load_lds with row-low-3-bit XOR chunk swizzle.
// Bias = MFMA C-init; exp immediately per nt; P UNNORMALIZED in half;
// 1/rowsum folded in during the O transpose. O-store is COALESCED: bounce
// 16x32 halves through the wave-private P buffer so each store instruction
// writes 64B-aligned full-line chunks (4 lanes x 16B per row) — fixes the
// 3.15x write amplification (round-12 WRITE_SIZE 122MB vs 38.7MB actual).
__global__ __launch_bounds__(832, 7) void attn_kernel(const _Float16* __restrict__ qh,
                                                      const _Float16* __restrict__ kh,
                                                      const _Float16* __restrict__ vt,
                                                      const _Float16* __restrict__ biasph,
                                                      _Float16* __restrict__ ah) {
    __shared__ __align__(16) _Float16 smem[38016];   // 76 KB: K 26.6K | V 32.8K | P 16.6K
    _Float16* Ks = smem;                  // [208][8 chunks swz]
    _Float16* Vs = smem + 13312;          // [64][32 chunks swz, 28 valid]
    _Float16* Pb = smem + 29696;          // [13][16][40]
    const int tid = threadIdx.x;
    const int w = tid >> 6, lane = tid & 63;
    const int r = lane & 15, q = lane >> 4;
    const int xr = r & 7;
    const int bh = ((blockIdx.x & 7) * 192) + (blockIdx.x >> 3);  // XCD-contiguous
    const int b = bh / NH, h = bh - b * NH;
    const _Float16* Kb = kh + (size_t)bh * NPAD * DH;
    const _Float16* Vtb = vt + (size_t)bh * DH * KPAD;

    // ---- stage K: 1664 slots, 2 exact full-wave rounds; src chunk = pos ^ (row&7)
#pragma unroll
    for (int rd = 0; rd < 2; ++rd) {
        int i = rd * 832 + tid;
        int g = i >> 3;
        int cs = (i & 7) ^ (g & 7);
        GLDS16(Kb + (size_t)g * DH + cs * 8, Ks + (rd * 832 + w * 64) * 8);
    }
    // ---- stage V: 2048 slots (pitch 32); rd=2 guard tid<384 = wave boundary
#pragma unroll
    for (int rd = 0; rd < 3; ++rd) {
        int j = rd * 832 + tid;
        if (j < 2048) {
            int g = j >> 5;
            int cs = (j & 31) ^ (g & 7);
            if (cs >= 28) cs = 0;       // branch-free select; slot never read
            GLDS16(Vtb + (size_t)g * KPAD + cs * 8, Vs + (rd * 832 + w * 64) * 8);
        }
    }
    __syncthreads();   // vmcnt(0) drain + barrier: staged data visible

    // ---- per-wave q-tile (qt = w) ----
    const int rowq = w * 16 + r;
    const _Float16* Qb = qh + (size_t)bh * NPAD * DH;
    half8 aq0 = *(const half8*)(Qb + (size_t)rowq * DH + q * 8);
    half8 aq1 = *(const half8*)(Qb + (size_t)rowq * DH + 32 + q * 8);

    // S = QK^T + bias (C-init), exp immediately -> unnormalized P (half)
    const _Float16* bbase = biasph + (((size_t)h * 13 + w) * 13) * 256 + r * 16 + q * 4;
    half4 pvh[NKT + 1];
    float osum[4] = {0.f, 0.f, 0.f, 0.f};
#pragma unroll
    for (int nt = 0; nt < NKT; ++nt) {
        half4 bv = *(const half4*)(bbase + nt * 256);
        floatx4 acc;
        acc[0] = (float)bv[0]; acc[1] = (float)bv[1];
        acc[2] = (float)bv[2]; acc[3] = (float)bv[3];
        const _Float16* kr = Ks + (nt * 16 + r) * 64;
        half8 b0 = *(const half8*)(kr + (q ^ xr) * 8);
        half8 b1 = *(const half8*)(kr + ((q ^ xr) ^ 4) * 8);
        acc = MFMA16(aq0, b0, acc);
        acc = MFMA16(aq1, b1, acc);
        half4 e4;
#pragma unroll
        for (int rr = 0; rr < 4; ++rr) {
            float e = __expf(acc[rr]);      // pad cols: exp(-30000) == 0 exactly
            osum[rr] += e;
            e4[rr] = (_Float16)e;
        }
        pvh[nt] = e4;
    }
    {
        half4 z = {};
        pvh[NKT] = z;                       // tail slot for kt=6
    }
    // row-sum across the 16 key-lanes (r bits 0..3)
#pragma unroll
    for (int rr = 0; rr < 4; ++rr) {
#pragma unroll
        for (int m = 1; m <= 8; m <<= 1) osum[rr] += __shfl_xor(osum[rr], m, 64);
    }

    // O = P V (P unnormalized), chunked over 7 x 32 keys; P via wave-private LDS
    floatx4 oacc[4] = {};
    _Float16* Pw = Pb + w * 640;
#pragma unroll
    for (int kt = 0; kt < 7; ++kt) {
#pragma unroll
        for (int rr = 0; rr < 4; ++rr) {
            Pw[(q * 4 + rr) * 40 + r] = pvh[kt * 2][rr];
            Pw[(q * 4 + rr) * 40 + 16 + r] = pvh[kt * 2 + 1][rr];
        }
        __asm__ volatile("" ::: "memory");   // keep ds_write -> ds_read order
        half8 ap = *(const half8*)&Pw[r * 40 + q * 8];
        __asm__ volatile("" ::: "memory");   // keep ds_read -> next writes order
#pragma unroll
        for (int dt = 0; dt < 4; ++dt) {
            half8 bv = *(const half8*)(Vs + (dt * 16 + r) * 256 + (((kt * 4 + q) ^ xr) * 8));
            oacc[dt] = MFMA16(ap, bv, oacc[dt]);
        }
    }

    // ---- coalesced O-store: normalize, transpose 16x32 through Pw, half8 out
    float inv[4];
#pragma unroll
    for (int rr = 0; rr < 4; ++rr) inv[rr] = 1.0f / osum[rr];
    const int lrow = lane >> 2;              // 0..15 (output row within q-tile)
    const int c0 = (lane & 3) * 8;           // 0..24 (col chunk within 32)
    const int orow = w * 16 + lrow;
#pragma unroll
    for (int hf = 0; hf < 2; ++hf) {
#pragma unroll
        for (int dtl = 0; dtl < 2; ++dtl) {
            int dt = hf * 2 + dtl;
#pragma unroll
            for (int rr = 0; rr < 4; ++rr)
                Pw[(q * 4 + rr) * 40 + dtl * 16 + r] = (_Float16)(oacc[dt][rr] * inv[rr]);
        }
        __asm__ volatile("" ::: "memory");   // ds_write -> ds_read order
        half8 hv = *(const half8*)&Pw[lrow * 40 + c0];
        __asm__ volatile("" ::: "memory");   // ds_read -> next pass writes
        if (orow < NTOK)
            *(half8*)&ah[((size_t)b * NTOK + orow) * DIM + h * DH + hf * 32 + c0] = hv;
    }
}

// ---------------- launch ----------------
extern "C" void kernel_launch(void* const* d_in, const int* in_sizes, int n_in,
                              void* d_out, int out_size, void* d_ws, size_t ws_size,
                              hipStream_t stream) {
    const float* x = (const float*)d_in[0];        // [128,197,768]
    const float* qkv_w = (const float*)d_in[1];    // [2304,768]
    const float* proj_w = (const float*)d_in[2];   // [768,768]
    const float* proj_b = (const float*)d_in[3];   // [768]
    const float* table = (const float*)d_in[4];    // [730,12]
    const int* ridx = (const int*)d_in[5];         // [197,197]
    float* out = (float*)d_out;

    char* ws = (char*)d_ws;
    const size_t SZ_XP = (size_t)MP_ROWS * DIM * 2;             // 40.9 MB (padded f16)
    const size_t SZ_WQKV = (size_t)3 * DIM * DIM * 2;           //  3.5 MB
    const size_t SZ_WPROJ = (size_t)DIM * DIM * 2;              //  1.2 MB
    const size_t SZ_QK = (size_t)BATCH * NH * NPAD * DH * 2;    // 40.9 MB each
    const size_t SZ_VT = (size_t)BATCH * NH * DH * KPAD * 2;    // 44.0 MB
    const size_t SZ_BIAS = (size_t)NH * 13 * 13 * 256 * 2;      //  1.0 MB

    _Float16* xh = (_Float16*)(ws + 0);
    _Float16* ah = (_Float16*)(ws + 0);              // aliases xh (x dead after qkv)
    _Float16* wqkvh = (_Float16*)(ws + SZ_XP);
    _Float16* wprojh = (_Float16*)(ws + SZ_XP + SZ_WQKV);
    _Float16* qh = (_Float16*)(ws + SZ_XP + SZ_WQKV + SZ_WPROJ);
    _Float16* kh = (_Float16*)(ws + SZ_XP + SZ_WQKV + SZ_WPROJ + SZ_QK);
    _Float16* vt = (_Float16*)(ws + SZ_XP + SZ_WQKV + SZ_WPROJ + 2 * SZ_QK);
    _Float16* biasph = (_Float16*)(ws + SZ_XP + SZ_WQKV + SZ_WPROJ + 2 * SZ_QK + SZ_VT);
    (void)SZ_BIAS; (void)ws_size; (void)n_in; (void)in_sizes; (void)out_size;

    // fused prep: x pad-convert + weight converts + bias pack + vt pad-col zero
    prep_kernel<<<(PREP_TOT + 255) / 256, 256, 0, stream>>>(
        x, qkv_w, proj_w, table, ridx, xh, wqkvh, wprojh, biasph, vt);
    // qkv gemm: 128x256 single-buffer tiles, 2 blocks/CU, 1872 blocks
    qkv_gemm8<<<1872, 512, 0, stream>>>(xh, wqkvh, qh, kh, vt);
    // attention: one block per (b,h), 13 waves, K/V LDS-staged
    attn_kernel<<<BATCH * NH, 832, 0, stream>>>(qh, kh, vt, biasph, ah);
    // proj gemm (XCD-swizzled, guarded)
    proj_gemm<<<1200, 256, 0, stream>>>(ah, wprojh, proj_b, out);
}